// Round 1
// baseline (192.918 us; speedup 1.0000x reference)
//
#include <hip/hip_runtime.h>
#include <hip/hip_bf16.h>
#include <stdint.h>

#define SEQ 2048
#define HID 2048
#define NH 16
#define HD 128
// 1/sqrt(128) * log2(e): softmax runs in exp2 domain
#define QSCALE_L2E 0.1275304429019769f

typedef __attribute__((ext_vector_type(4))) float f32x4;
typedef __attribute__((ext_vector_type(8))) short short8;
typedef __attribute__((ext_vector_type(4))) float f4;
typedef __attribute__((ext_vector_type(4))) unsigned short us4;

__device__ __forceinline__ unsigned short f2bu(float f) {
  union { float f; unsigned int u; } c; c.f = f;
  unsigned int u = c.u + 0x7fffu + ((c.u >> 16) & 1u);  // RNE, finite inputs
  return (unsigned short)(u >> 16);
}

__device__ __forceinline__ unsigned short f2bu_fast(float f) {
  union { float f; unsigned int u; } c; c.f = f;
  return (unsigned short)((c.u + 0x8000u) >> 16);
}

__device__ __forceinline__ float b2f(unsigned short u) {
  union { unsigned int u; float f; } c; c.u = ((unsigned int)u) << 16; return c.f;
}

__device__ __forceinline__ float exp2fast(float x) {
  float r; asm("v_exp_f32 %0, %1" : "=v"(r) : "v"(x)); return r;
}

__device__ __forceinline__ void gload_lds16(const void* g, void* l) {
  __builtin_amdgcn_global_load_lds((const __attribute__((address_space(1))) void*)g,
                                   (__attribute__((address_space(3))) void*)l, 16, 0, 0);
}

#define BAR() __builtin_amdgcn_s_barrier()
#define LGKM0() do { asm volatile("s_waitcnt lgkmcnt(0)" ::: "memory"); __builtin_amdgcn_sched_barrier(0); } while (0)
#define VM6()   do { asm volatile("s_waitcnt vmcnt(6)"   ::: "memory"); __builtin_amdgcn_sched_barrier(0); } while (0)
#define VM0()   do { asm volatile("s_waitcnt vmcnt(0)"   ::: "memory"); __builtin_amdgcn_sched_barrier(0); } while (0)

// ---------------- fp32 -> bf16 convert, 5 equal-size arrays (32B/thread) ----
__global__ __launch_bounds__(256) void cvt_kernel(
    const float* __restrict__ s0, const float* __restrict__ s1,
    const float* __restrict__ s2, const float* __restrict__ s3,
    const float* __restrict__ s4,
    unsigned short* __restrict__ d0, unsigned short* __restrict__ d1,
    unsigned short* __restrict__ d2, unsigned short* __restrict__ d3,
    unsigned short* __restrict__ d4, int n)
{
  const float* s; unsigned short* d;
  switch (blockIdx.y) {
    case 0: s = s0; d = d0; break;
    case 1: s = s1; d = d1; break;
    case 2: s = s2; d = d2; break;
    case 3: s = s3; d = d3; break;
    default: s = s4; d = d4; break;
  }
  const int stride = gridDim.x * blockDim.x;
  for (int i = blockIdx.x * blockDim.x + threadIdx.x; i * 8 < n; i += stride) {
    f4 v0 = *(const f4*)&s[i * 8];
    f4 v1 = *(const f4*)&s[i * 8 + 4];
    short8 o;
    o[0] = (short)f2bu(v0[0]); o[1] = (short)f2bu(v0[1]);
    o[2] = (short)f2bu(v0[2]); o[3] = (short)f2bu(v0[3]);
    o[4] = (short)f2bu(v1[0]); o[5] = (short)f2bu(v1[1]);
    o[6] = (short)f2bu(v1[2]); o[7] = (short)f2bu(v1[3]);
    *(short8*)&d[i * 8] = o;
  }
}

// ---------------- 256x256 bf16 GEMM, 8-phase schedule  C = A*B^T + bias -----
// R15: port of the verified 256^2 8-phase template (T2 swizzle + T3/T4
// counted-vmcnt + T5 setprio). 8 waves (2M x 4N), per-wave 128x64 output,
// BK=64, 128 KiB LDS double-buffer. Per K-tile: 4 phases x 16 MFMA, one
// half-tile (2 gload_lds/thread) staged per phase, single vmcnt(6) at P4
// (3 half-tiles stay in flight; never drains in main loop).
// LDS element map (bf16): buf c at c*32768:
//   A half h: +h*8192 ; B half h: +16384+h*8192 ; stage region (c_,w): +(c_*8+w)*512
// Swizzle (same both sides, proven 0-conflict in R14): 16B-block b of row r
// stored at b^(r&7); staging pre-swizzles the GLOBAL column instead.
template<int MODE>
__global__ __launch_bounds__(512, 2) void gemm256(
    const unsigned short* __restrict__ A,
    const unsigned short* __restrict__ B,
    const float* __restrict__ b0, const float* __restrict__ b1, const float* __restrict__ b2,
    unsigned short* __restrict__ O0, unsigned short* __restrict__ O1, unsigned short* __restrict__ O2,
    float* __restrict__ Of, int M, int N, int K)
{
  extern __shared__ unsigned short lds[];
  const int tid = threadIdx.x;
  const int l = tid & 63, w = tid >> 6;          // 8 waves
  const int g = l >> 4, q = l & 15;
  const int wgM = w >> 2, wgN = w & 3;           // 2M x 4N wave grid
  const long bm = (long)blockIdx.y * 256, bn = (long)blockIdx.x * 256;
  const int NK = K >> 6;

  // staging lane geometry: lane l writes LDS row (l>>3), 16B-block (l&7);
  // stored block = orig ^ (row&7)  =>  load global block (l&7)^(l>>3)
  const int srl = l >> 3;
  const int scE = ((l & 7) ^ srl) * 8;
  const unsigned short* aG = A + (bm + w * 8 + srl) * (long)K + scE;
  const unsigned short* bG = B + (bn + w * 8 + srl) * (long)K + scE;
  const int stReg = w * 512;                     // + c_*4096 elements

  // read-side: frag row = <base> + q, k-block kh*4+g, stored ^ (q&7)
  const int cA0 = (g ^ (q & 7)) * 8;             // kh=0 ; kh=1 is ^32
  const int rowA = (wgM * 64 + q) * 64;          // + mi*1024
  const int rowB = (wgN * 32 + q) * 64;          // + ni*1024

  f32x4 acc[8][4] = {};
  short8 a[4][2], bb[4][2];

#define STG(gp, halfRow, jj, ldsEl)                                           \
  do {                                                                        \
    _Pragma("unroll")                                                         \
    for (int c_ = 0; c_ < 2; ++c_)                                            \
      gload_lds16((gp) + ((long)((halfRow) + c_ * 64)) * K + (jj) * 64,       \
                  &lds[(ldsEl) + c_ * 4096 + stReg]);                         \
  } while (0)

#define LDA(h, be)                                                            \
  do { const unsigned short* At_ = &lds[(be) + (h) * 8192 + rowA];            \
    _Pragma("unroll")                                                         \
    for (int mi_ = 0; mi_ < 4; ++mi_) {                                       \
      a[mi_][0] = *(const short8*)&At_[mi_ * 1024 + cA0];                     \
      a[mi_][1] = *(const short8*)&At_[mi_ * 1024 + (cA0 ^ 32)];              \
    } } while (0)

#define LDB(h, be)                                                            \
  do { const unsigned short* Bt_ = &lds[(be) + 16384 + (h) * 8192 + rowB];    \
    _Pragma("unroll")                                                         \
    for (int ni_ = 0; ni_ < 2; ++ni_) {                                       \
      bb[(h) * 2 + ni_][0] = *(const short8*)&Bt_[ni_ * 1024 + cA0];          \
      bb[(h) * 2 + ni_][1] = *(const short8*)&Bt_[ni_ * 1024 + (cA0 ^ 32)];   \
    } } while (0)

#define MF16(mb, nA, nB)                                                      \
  do { __builtin_amdgcn_s_setprio(1);                                         \
    _Pragma("unroll")                                                         \
    for (int mi_ = 0; mi_ < 4; ++mi_) {                                       \
      acc[(mb) + mi_][nA] = __builtin_amdgcn_mfma_f32_16x16x32_bf16(          \
          a[mi_][0], bb[nA][0], acc[(mb) + mi_][nA], 0, 0, 0);                \
      acc[(mb) + mi_][nA] = __builtin_amdgcn_mfma_f32_16x16x32_bf16(          \
          a[mi_][1], bb[nA][1], acc[(mb) + mi_][nA], 0, 0, 0);                \
      acc[(mb) + mi_][nB] = __builtin_amdgcn_mfma_f32_16x16x32_bf16(          \
          a[mi_][0], bb[nB][0], acc[(mb) + mi_][nB], 0, 0, 0);                \
      acc[(mb) + mi_][nB] = __builtin_amdgcn_mfma_f32_16x16x32_bf16(          \
          a[mi_][1], bb[nB][1], acc[(mb) + mi_][nB], 0, 0, 0);                \
    }                                                                         \
    __builtin_amdgcn_s_setprio(0); } while (0)

  // ---- prologue: tile0 (4 halves) + tile1 {A0,B0,B1} -> 14 loads; wait
  // oldest 8 (tile0) via vmcnt(6)
  STG(aG, 0,   0, 0);
  STG(aG, 128, 0, 8192);
  STG(bG, 0,   0, 16384);
  STG(bG, 128, 0, 24576);
  if (NK > 1) {
    STG(aG, 0,   1, 32768);
    STG(bG, 0,   1, 32768 + 16384);
    STG(bG, 128, 1, 32768 + 24576);
    VM6();
  } else {
    VM0();
  }
  BAR();

  for (int j = 0; j < NK; ++j) {
    const int b0e = (j & 1) << 15;     // this tile's buffer (elements)
    const int b1e = b0e ^ 32768;       // next tile's buffer

    // P1: read A-half0 + B-half0 ; stage A1(j+1) (region freed at P3(j-1))
    LDA(0, b0e); LDB(0, b0e);
    if (j + 1 < NK) STG(aG, 128, j + 1, b1e + 8192);
    BAR(); LGKM0();
    MF16(0, 0, 1);
    BAR();

    // P2: read B-half1 ; stage A0(j+2) into this buffer (A0 freed after P1)
    LDB(1, b0e);
    if (j + 2 < NK) STG(aG, 0, j + 2, b0e);
    BAR(); LGKM0();
    MF16(0, 2, 3);
    BAR();

    // P3: read A-half1 ; stage B0(j+2) (B0 freed after P1)
    LDA(1, b0e);
    if (j + 2 < NK) STG(bG, 0, j + 2, b0e + 16384);
    BAR(); LGKM0();
    MF16(4, 0, 1);
    BAR();

    // P4: no ds reads ; stage B1(j+2) (B1 freed after P2) ; counted vmcnt
    if (j + 2 < NK) STG(bG, 128, j + 2, b0e + 24576);
    BAR();
    MF16(4, 2, 3);
    if (j + 2 < NK) { VM6(); } else { VM0(); }
    BAR();
  }

  // ---- epilogue ----
#pragma unroll
  for (int ni = 0; ni < 4; ++ni) {
    const int col = (int)bn + (ni >> 1) * 128 + wgN * 32 + (ni & 1) * 16 + q;
    float bv;
    if (MODE == 4) {
      const int which = col >> 11, c = col & 2047;
      const float* bp = which == 0 ? b0 : (which == 1 ? b1 : b2);
      bv = bp[c];
    } else {
      bv = b0[col];
    }
#pragma unroll
    for (int mi = 0; mi < 8; ++mi) {
      const long row0 = bm + (mi >> 2) * 128 + wgM * 64 + (mi & 3) * 16 + 4 * g;
#pragma unroll
      for (int r = 0; r < 4; ++r) {
        const long row = row0 + r;
        const float v = acc[mi][ni][r] + bv;
        if (MODE == 4) {
          const int which = col >> 11, c = col & 2047, head = c >> 7, d = c & 127;
          if (which == 0)      O0[((long)head * SEQ + row) * HD + d] = f2bu(v * QSCALE_L2E);
          else if (which == 1) O1[((long)head * SEQ + row) * HD + d] = f2bu(v);
          else                 O2[((long)head * HD + d) * SEQ + row] = f2bu(v);
        } else {
          Of[row * (long)N + col] = v;
        }
      }
    }
  }
#undef STG
#undef LDA
#undef LDB
#undef MF16
}

// ---------------- 64x128 bf16 GEMM  C = A[M,K] * B[N,K]^T + bias ------------
// Kept for the out-projection (2048x2048: 512 blocks of 64x128 fits the grid
// better than 64 blocks of 256^2).
template<int MODE>
__global__ __launch_bounds__(256, 2) void gemm128(
    const unsigned short* __restrict__ A,
    const unsigned short* __restrict__ B,
    const float* __restrict__ b0, const float* __restrict__ b1, const float* __restrict__ b2,
    unsigned short* __restrict__ O0, unsigned short* __restrict__ O1, unsigned short* __restrict__ O2,
    float* __restrict__ Of, int M, int N, int K)
{
  constexpr int ASZ = 64 * 64;
  constexpr int BSZ = 128 * 64;

  extern __shared__ unsigned short lds[];
  const int tid = threadIdx.x;
  const int lane = tid & 63, w = tid >> 6;
  const int g = lane >> 4, q = lane & 15;
  const long bm = (long)blockIdx.y * 64, bn = (long)blockIdx.x * 128;
  const int NK = K >> 6;

  const int srl = lane >> 3;
  const int scE = ((lane & 7) ^ srl) * 8;
  const int c0 = (g ^ (q & 7)) * 8;
  const int c1 = c0 ^ 32;
  const int aB = q * 64;
  const int bB = (w * 32 + q) * 64;

  f32x4 acc[4][2] = {};
  short8 a[4][2], b[2][2];

#define STAGE_A(jj) do {                                                      \
    unsigned short* dst_ = lds + (((jj) & 1) ? ASZ : 0);                      \
    _Pragma("unroll")                                                         \
    for (int c_ = 0; c_ < 2; ++c_) {                                          \
      const long row_ = (c_ * 4 + w) * 8 + srl;                               \
      gload_lds16(&A[(bm + row_) * (long)K + (jj) * 64 + scE],                \
                  &dst_[(c_ * 4 + w) * 512]);                                 \
    }                                                                         \
  } while (0)

#define STAGE_B(jj) do {                                                      \
    unsigned short* dst_ = lds + 2 * ASZ + (((jj) & 1) ? BSZ : 0);            \
    _Pragma("unroll")                                                         \
    for (int c_ = 0; c_ < 4; ++c_) {                                          \
      const long row_ = (c_ * 4 + w) * 8 + srl;                               \
      gload_lds16(&B[(bn + row_) * (long)K + (jj) * 64 + scE],                \
                  &dst_[(c_ * 4 + w) * 512]);                                 \
    }                                                                         \
  } while (0)

#define QUAD8(ni)                                                             \
  do {                                                                        \
    __builtin_amdgcn_s_setprio(1);                                            \
    _Pragma("unroll")                                                         \
    for (int mi_ = 0; mi_ < 4; ++mi_) {                                       \
      acc[mi_][ni] = __builtin_amdgcn_mfma_f32_16x16x32_bf16(                 \
          a[mi_][0], b[ni][0], acc[mi_][ni], 0, 0, 0);                        \
      acc[mi_][ni] = __builtin_amdgcn_mfma_f32_16x16x32_bf16(                 \
          a[mi_][1], b[ni][1], acc[mi_][ni], 0, 0, 0);                        \
    }                                                                         \
    __builtin_amdgcn_s_setprio(0);                                            \
  } while (0)

  STAGE_A(0); STAGE_B(0);
  STAGE_A(1); STAGE_B(1);
  VM6();
  BAR();

  for (int j = 0; j < NK; ++j) {
    unsigned short* At = lds + ((j & 1) ? ASZ : 0);
    unsigned short* Bt = lds + 2 * ASZ + ((j & 1) ? BSZ : 0);

#pragma unroll
    for (int mi = 0; mi < 4; ++mi) {
      a[mi][0] = *(const short8*)&At[aB + mi * 1024 + c0];
      a[mi][1] = *(const short8*)&At[aB + mi * 1024 + c1];
    }
#pragma unroll
    for (int ni = 0; ni < 2; ++ni) {
      b[ni][0] = *(const short8*)&Bt[bB + ni * 1024 + c0];
      b[ni][1] = *(const short8*)&Bt[bB + ni * 1024 + c1];
    }
    QUAD8(0);
    LGKM0();
    BAR();                                  // (a)
    if (j + 2 < NK) { STAGE_A(j + 2); STAGE_B(j + 2); }
    QUAD8(1);
    if (j < NK - 2) { VM6(); } else { VM0(); }
    BAR();                                  // (b)
  }

#pragma unroll
  for (int ni = 0; ni < 2; ++ni) {
    const int col = (int)bn + w * 32 + ni * 16 + q;
    float bv;
    if (MODE == 4) {
      const int which = col >> 11, c = col & 2047;
      const float* bp = which == 0 ? b0 : (which == 1 ? b1 : b2);
      bv = bp[c];
    } else {
      bv = b0[col];
    }
#pragma unroll
    for (int mi = 0; mi < 4; ++mi)
#pragma unroll
      for (int r = 0; r < 4; ++r) {
        const long row = bm + mi * 16 + 4 * g + r;
        const float v = acc[mi][ni][r] + bv;
        if (MODE == 4) {
          const int which = col >> 11, c = col & 2047, head = c >> 7, d = c & 127;
          if (which == 0)      O0[((long)head * SEQ + row) * HD + d] = f2bu(v * QSCALE_L2E);
          else if (which == 1) O1[((long)head * SEQ + row) * HD + d] = f2bu(v);
          else                 O2[((long)head * HD + d) * SEQ + row] = f2bu(v);
        } else {
          Of[row * (long)N + col] = v;
        }
      }
  }
#undef STAGE_A
#undef STAGE_B
#undef QUAD8
}

// ---------------- flash attention v5 ----------------------------------------
// R8/R11-verified structure; Po partials bf16 (halves partial traffic).
#define KVB 64
__global__ __launch_bounds__(256) void flash_attn(
    const unsigned short* __restrict__ Qb,
    const unsigned short* __restrict__ Kb,
    const unsigned short* __restrict__ VTb,
    unsigned short* __restrict__ Po,         // [NH][32][2][64][128] bf16
    float* __restrict__ Pl)                  // [NH][32][2][64] f32
{
  __shared__ __align__(16) unsigned short Kt[64 * 128];
  __shared__ __align__(16) unsigned short Vt[128 * 64];
  __shared__ __align__(16) unsigned short Pt[4][16 * 64];
  const int tid = threadIdx.x;
  const int l = tid & 63, w = tid >> 6;
  const int g = l >> 4, q = l & 15;
  const int h = blockIdx.y, qb = blockIdx.x, half = blockIdx.z;
  const int qrow0 = qb * 64 + w * 16;

  short8 qf[4];
#pragma unroll
  for (int dc = 0; dc < 4; ++dc)
    qf[dc] = *(const short8*)&Qb[((long)h * SEQ + qrow0 + q) * HD + dc * 32 + g * 8];

  f32x4 oacc[8] = {};
  float lsum[4] = {0.f, 0.f, 0.f, 0.f};

  const int kr = tid >> 4, kc16 = tid & 15;
  const int vr = tid >> 3, vc8 = tid & 7;
  const unsigned short* Kg = Kb + (long)h * SEQ * HD + (long)half * 1024 * HD;
  const unsigned short* Vg = VTb + (long)h * HD * SEQ + half * 1024;

  short8 kreg[4], vreg[4];
#pragma unroll
  for (int it = 0; it < 4; ++it) {
    kreg[it] = *(const short8*)&Kg[(long)(kr + it * 16) * HD + kc16 * 8];
    vreg[it] = *(const short8*)&Vg[(long)(vr + it * 32) * SEQ + vc8 * 8];
  }

  for (int kb = 0; kb < 1024; kb += KVB) {
    __syncthreads();
#pragma unroll
    for (int it = 0; it < 4; ++it) {
      const int krow = kr + it * 16;
      *(short8*)&Kt[((krow * 256 + kc16 * 16) ^ ((krow & 7) << 4)) >> 1] = kreg[it];
      const int vrow = vr + it * 32;
      *(short8*)&Vt[((vrow * 128 + vc8 * 16) ^ ((vrow & 7) << 4)) >> 1] = vreg[it];
    }
    __syncthreads();
    if (kb + KVB < 1024) {
#pragma unroll
      for (int it = 0; it < 4; ++it) {
        kreg[it] = *(const short8*)&Kg[(long)(kb + KVB + kr + it * 16) * HD + kc16 * 8];
        vreg[it] = *(const short8*)&Vg[(long)(vr + it * 32) * SEQ + kb + KVB + vc8 * 8];
      }
    }

    f32x4 sacc[4] = {};
#pragma unroll
    for (int kc = 0; kc < 4; ++kc) {
      const int krow = kc * 16 + q;
      const int sw = (krow & 7) << 4;
#pragma unroll
      for (int dc = 0; dc < 4; ++dc) {
        short8 kf = *(const short8*)&Kt[((krow * 256 + dc * 64 + g * 16) ^ sw) >> 1];
        sacc[kc] = __builtin_amdgcn_mfma_f32_16x16x32_bf16(qf[dc], kf, sacc[kc], 0, 0, 0);
      }
    }

    float p[4][4];
#pragma unroll
    for (int r = 0; r < 4; ++r) {
#pragma unroll
      for (int kc = 0; kc < 4; ++kc) p[kc][r] = exp2fast(sacc[kc][r]);
      lsum[r] += (p[0][r] + p[1][r]) + (p[2][r] + p[3][r]);
    }

    unsigned short* Pw = &Pt[w][0];
#pragma unroll
    for (int r = 0; r < 4; ++r) {
      const int prow = 4 * g + r;
      const int sw = (prow & 7) << 4;
#pragma unroll
      for (int kc = 0; kc < 4; ++kc)
        Pw[((prow * 128 + (kc * 16 + q) * 2) ^ sw) >> 1] = f2bu_fast(p[kc][r]);
    }

    short8 pf[2];
    const int psw = (q & 7) << 4;
#pragma unroll
    for (int ks = 0; ks < 2; ++ks)
      pf[ks] = *(const short8*)&Pw[((q * 128 + ks * 64 + g * 16) ^ psw) >> 1];
#pragma unroll
    for (int dt = 0; dt < 8; ++dt) {
      const int vrow = dt * 16 + q;
#pragma unroll
      for (int ks = 0; ks < 2; ++ks) {
        short8 vf = *(const short8*)&Vt[((vrow * 128 + ks * 64 + g * 16) ^ psw) >> 1];
        oacc[dt] = __builtin_amdgcn_mfma_f32_16x16x32_bf16(pf[ks], vf, oacc[dt], 0, 0, 0);
      }
    }
  }

#pragma unroll
  for (int off = 1; off < 16; off <<= 1)
#pragma unroll
    for (int r = 0; r < 4; ++r) lsum[r] += __shfl_xor(lsum[r], off);

  const long tI = ((long)h * 32 + qb) * 2 + half;
  unsigned short* PoT = Po + tI * 8192;
#pragma unroll
  for (int dt = 0; dt < 8; ++dt)
#pragma unroll
    for (int r = 0; r < 4; ++r)
      PoT[(w * 16 + 4 * g + r) * 128 + dt * 16 + q] = f2bu_fast(oacc[dt][r]);
  if (q == 0) {
#pragma unroll
    for (int r = 0; r < 4; ++r)
      Pl[tI * 64 + w * 16 + 4 * g + r] = lsum[r];
  }
}

// ---------------- combine bf16 partials -> Attn bf16 ------------------------
__global__ __launch_bounds__(256) void combine_kernel(
    const unsigned short* __restrict__ Po, const float* __restrict__ Pl,
    unsigned short* __restrict__ attnb)
{
  const int qb = blockIdx.x, h = blockIdx.y;
  const long tI = ((long)h * 32 + qb) * 2;
  const unsigned short* A0 = Po + tI * 8192;
  const unsigned short* A1 = Po + (tI + 1) * 8192;
  const float* L0 = Pl + tI * 64;
  const float* L1 = Pl + (tI + 1) * 64;
  const int tid = threadIdx.x;
#pragma unroll
  for (int k = 0; k < 8; ++k) {
    const int i = tid + k * 256;          // us4 group within [64][32]
    const int row = i >> 5, c4 = i & 31;
    const us4 a = *(const us4*)&A0[i * 4];
    const us4 b = *(const us4*)&A1[i * 4];
    const float rl = 1.f / (L0[row] + L1[row]);
    us4 o;
    o[0] = f2bu((b2f(a[0]) + b2f(b[0])) * rl);
    o[1] = f2bu((b2f(a[1]) + b2f(b[1])) * rl);
    o[2] = f2bu((b2f(a[2]) + b2f(b[2])) * rl);
    o[3] = f2bu((b2f(a[3]) + b2f(b[3])) * rl);
    *(us4*)&attnb[(long)(qb * 64 + row) * HID + h * HD + c4 * 4] = o;
  }
}

extern "C" void kernel_launch(void* const* d_in, const int* in_sizes, int n_in,
                              void* d_out, int out_size, void* d_ws, size_t ws_size,
                              hipStream_t stream)
{
  const float* x  = (const float*)d_in[0];
  const float* wq = (const float*)d_in[1];
  const float* bq = (const float*)d_in[2];
  const float* wk = (const float*)d_in[3];
  const float* bk = (const float*)d_in[4];
  const float* wv = (const float*)d_in[5];
  const float* bv = (const float*)d_in[6];
  const float* wo = (const float*)d_in[7];
  const float* bo = (const float*)d_in[8];

  const long NEL = (long)HID * HID;
  unsigned short* Xb   = (unsigned short*)d_ws;
  unsigned short* Wqkv = Xb + NEL;
  unsigned short* Wob  = Wqkv + 3 * NEL;
  unsigned short* Qbuf = Wob + NEL;
  unsigned short* Kbuf = Qbuf + NEL;
  unsigned short* VTb  = Kbuf + NEL;
  unsigned short* Attn = VTb + NEL;

  // Po (16.8MB bf16) overlays [Xb, Xb+2*NEL) — dead after QKV GEMM.
  // Pl (256KB f32) lives at the start of d_out — fully overwritten by out-proj.
  unsigned short* Po = (unsigned short*)d_ws;
  float* Pl = (float*)d_out;

  // one-time opt-in for 128 KiB dynamic LDS (host-side, not a stream op —
  // graph-capture safe)
  static bool attrDone = false;
  if (!attrDone) {
    hipFuncSetAttribute(reinterpret_cast<const void*>(gemm256<4>),
                        hipFuncAttributeMaxDynamicSharedMemorySize, 131072);
    attrDone = true;
  }

  cvt_kernel<<<dim3(512, 5), 256, 0, stream>>>(
      x, wq, wk, wv, wo, Xb, Wqkv, Wqkv + NEL, Wqkv + 2 * NEL, Wob, (int)NEL);

  gemm256<4><<<dim3(24, 8), 512, 131072, stream>>>(
      Xb, Wqkv, bq, bk, bv, Qbuf, Kbuf, VTb, nullptr, SEQ, 3 * HID, HID);

  flash_attn<<<dim3(SEQ / 64, NH, 2), 256, 0, stream>>>(Qbuf, Kbuf, VTb, Po, Pl);

  combine_kernel<<<dim3(SEQ / 64, NH), 256, 0, stream>>>(Po, Pl, Attn);

  gemm128<3><<<dim3(16, 32), 256, 49152, stream>>>(
      Attn, Wob, bo, nullptr, nullptr, nullptr, nullptr, nullptr,
      (float*)d_out, SEQ, HID, HID);
}

// Round 2
// 185.523 us; speedup vs baseline: 1.0399x; 1.0399x over previous
//
#include <hip/hip_runtime.h>
#include <hip/hip_bf16.h>
#include <stdint.h>

#define SEQ 2048
#define HID 2048
#define NH 16
#define HD 128
// 1/sqrt(128) * log2(e): softmax runs in exp2 domain
#define QSCALE_L2E 0.1275304429019769f

typedef __attribute__((ext_vector_type(4))) float f32x4;
typedef __attribute__((ext_vector_type(8))) short short8;
typedef __attribute__((ext_vector_type(4))) float f4;
typedef __attribute__((ext_vector_type(4))) unsigned short us4;

__device__ __forceinline__ unsigned short f2bu(float f) {
  union { float f; unsigned int u; } c; c.f = f;
  unsigned int u = c.u + 0x7fffu + ((c.u >> 16) & 1u);  // RNE, finite inputs
  return (unsigned short)(u >> 16);
}

__device__ __forceinline__ unsigned short f2bu_fast(float f) {
  union { float f; unsigned int u; } c; c.f = f;
  return (unsigned short)((c.u + 0x8000u) >> 16);
}

__device__ __forceinline__ float b2f(unsigned short u) {
  union { unsigned int u; float f; } c; c.u = ((unsigned int)u) << 16; return c.f;
}

__device__ __forceinline__ float exp2fast(float x) {
  float r; asm("v_exp_f32 %0, %1" : "=v"(r) : "v"(x)); return r;
}

__device__ __forceinline__ void gload_lds16(const void* g, void* l) {
  __builtin_amdgcn_global_load_lds((const __attribute__((address_space(1))) void*)g,
                                   (__attribute__((address_space(3))) void*)l, 16, 0, 0);
}

#define BAR() __builtin_amdgcn_s_barrier()
#define LGKM0() do { asm volatile("s_waitcnt lgkmcnt(0)" ::: "memory"); __builtin_amdgcn_sched_barrier(0); } while (0)
#define VM8()   do { asm volatile("s_waitcnt vmcnt(8)"   ::: "memory"); __builtin_amdgcn_sched_barrier(0); } while (0)
#define VM0()   do { asm volatile("s_waitcnt vmcnt(0)"   ::: "memory"); __builtin_amdgcn_sched_barrier(0); } while (0)

// ---------------- fp32 -> bf16 convert, 5 equal-size arrays (32B/thread) ----
__global__ __launch_bounds__(256) void cvt_kernel(
    const float* __restrict__ s0, const float* __restrict__ s1,
    const float* __restrict__ s2, const float* __restrict__ s3,
    const float* __restrict__ s4,
    unsigned short* __restrict__ d0, unsigned short* __restrict__ d1,
    unsigned short* __restrict__ d2, unsigned short* __restrict__ d3,
    unsigned short* __restrict__ d4, int n)
{
  const float* s; unsigned short* d;
  switch (blockIdx.y) {
    case 0: s = s0; d = d0; break;
    case 1: s = s1; d = d1; break;
    case 2: s = s2; d = d2; break;
    case 3: s = s3; d = d3; break;
    default: s = s4; d = d4; break;
  }
  const int stride = gridDim.x * blockDim.x;
  for (int i = blockIdx.x * blockDim.x + threadIdx.x; i * 8 < n; i += stride) {
    f4 v0 = *(const f4*)&s[i * 8];
    f4 v1 = *(const f4*)&s[i * 8 + 4];
    short8 o;
    o[0] = (short)f2bu(v0[0]); o[1] = (short)f2bu(v0[1]);
    o[2] = (short)f2bu(v0[2]); o[3] = (short)f2bu(v0[3]);
    o[4] = (short)f2bu(v1[0]); o[5] = (short)f2bu(v1[1]);
    o[6] = (short)f2bu(v1[2]); o[7] = (short)f2bu(v1[3]);
    *(short8*)&d[i * 8] = o;
  }
}

// ---------------- 128x128 bf16 GEMM  C = A[M,K] * B[N,K]^T + bias -----------
// R16: widened R14-proven structure. BM=BN=128, BK=64, 4 waves (2Mx2N),
// per-wave 64x64 output (acc[4][4]) -> MFMA:ds_read = 32:16 per K-tile
// (2x the 64x128 kernel's 16:12). LDS 64KB dbuf -> 2 blocks/CU so the two
// resident blocks overlap MFMA and LDS phases across blocks (m114 effect).
// Loop skeleton identical to the R14-verified one:
//   reads -> QUAD(n0,n1) (compiler partial-lgkm interleave) -> LGKM0 ->
//   BAR(a) -> stage(j+2) into CURRENT buffer -> QUAD(n2,n3) -> VM8 -> BAR(b)
// Staging: 8 gload_lds/thread per K-tile (A:4 + B:4); counted wait vmcnt(8)
// keeps tile j+2's loads in flight across the barrier.
template<int MODE>
__global__ __launch_bounds__(256, 2) void gemm128sq(
    const unsigned short* __restrict__ A,
    const unsigned short* __restrict__ B,
    const float* __restrict__ b0, const float* __restrict__ b1, const float* __restrict__ b2,
    unsigned short* __restrict__ O0, unsigned short* __restrict__ O1, unsigned short* __restrict__ O2,
    float* __restrict__ Of, int M, int N, int K)
{
  constexpr int TSZ = 128 * 64;            // elements per tile buffer (16KB)

  extern __shared__ unsigned short lds[];  // [A0 A1 B0 B1] = 64KB
  const int tid = threadIdx.x;
  const int lane = tid & 63, w = tid >> 6;
  const int g = lane >> 4, q = lane & 15;
  const int wgM = w >> 1, wgN = w & 1;     // 2M x 2N wave grid
  const long bm = (long)blockIdx.y * 128, bn = (long)blockIdx.x * 128;
  const int NK = K >> 6;

  // staging lane geometry (proven): lane writes LDS row (l>>3), 16B-block
  // (l&7); global column block pre-swizzled: (l&7)^(l>>3)
  const int srl = lane >> 3;
  const int scE = ((lane & 7) ^ srl) * 8;
  // fragment read swizzle: logical k-block g of row r stored at g^(r&7);
  // all frag rows have row&7 == q&7
  const int c0 = (g ^ (q & 7)) * 8;
  const int c1 = c0 ^ 32;
  const int aB = (wgM * 64 + q) * 64;
  const int bB = (wgN * 64 + q) * 64;

  f32x4 acc[4][4] = {};
  short8 a[4][2], b[4][2];

#define STAGE(gp, gbase, jj, ldsOff) do {                                     \
    unsigned short* dst_ = lds + (ldsOff) + (((jj) & 1) ? TSZ : 0);           \
    _Pragma("unroll")                                                         \
    for (int c_ = 0; c_ < 4; ++c_) {                                          \
      const long row_ = (c_ * 4 + w) * 8 + srl;                               \
      gload_lds16(&(gp)[((gbase) + row_) * (long)K + (jj) * 64 + scE],        \
                  &dst_[(c_ * 4 + w) * 512]);                                 \
    }                                                                         \
  } while (0)

#define QUADD(n0, n1)                                                         \
  do {                                                                        \
    __builtin_amdgcn_s_setprio(1);                                            \
    _Pragma("unroll")                                                         \
    for (int mi_ = 0; mi_ < 4; ++mi_) {                                       \
      acc[mi_][n0] = __builtin_amdgcn_mfma_f32_16x16x32_bf16(                 \
          a[mi_][0], b[n0][0], acc[mi_][n0], 0, 0, 0);                        \
      acc[mi_][n0] = __builtin_amdgcn_mfma_f32_16x16x32_bf16(                 \
          a[mi_][1], b[n0][1], acc[mi_][n0], 0, 0, 0);                        \
      acc[mi_][n1] = __builtin_amdgcn_mfma_f32_16x16x32_bf16(                 \
          a[mi_][0], b[n1][0], acc[mi_][n1], 0, 0, 0);                        \
      acc[mi_][n1] = __builtin_amdgcn_mfma_f32_16x16x32_bf16(                 \
          a[mi_][1], b[n1][1], acc[mi_][n1], 0, 0, 0);                        \
    }                                                                         \
    __builtin_amdgcn_s_setprio(0);                                            \
  } while (0)

  STAGE(A, bm, 0, 0); STAGE(B, bn, 0, 2 * TSZ);
  STAGE(A, bm, 1, 0); STAGE(B, bn, 1, 2 * TSZ);
  VM8();                                     // tile0's 8 loads complete
  BAR();

  for (int j = 0; j < NK; ++j) {
    const unsigned short* At = lds + ((j & 1) ? TSZ : 0);
    const unsigned short* Bt = lds + 2 * TSZ + ((j & 1) ? TSZ : 0);

#pragma unroll
    for (int mi = 0; mi < 4; ++mi) {
      a[mi][0] = *(const short8*)&At[aB + mi * 1024 + c0];
      a[mi][1] = *(const short8*)&At[aB + mi * 1024 + c1];
    }
#pragma unroll
    for (int ni = 0; ni < 4; ++ni) {
      b[ni][0] = *(const short8*)&Bt[bB + ni * 1024 + c0];
      b[ni][1] = *(const short8*)&Bt[bB + ni * 1024 + c1];
    }
    QUADD(0, 1);
    LGKM0();                                // all 16 reads of this buffer done
    BAR();                                  // (a) -> safe to overwrite buffer
    if (j + 2 < NK) { STAGE(A, bm, j + 2, 0); STAGE(B, bn, j + 2, 2 * TSZ); }
    QUADD(2, 3);
    if (j < NK - 2) { VM8(); } else { VM0(); }   // tile j+1 landed
    BAR();                                  // (b)
  }

#pragma unroll
  for (int ni = 0; ni < 4; ++ni) {
    const int col = (int)bn + wgN * 64 + ni * 16 + q;
    float bv;
    if (MODE == 4) {
      const int which = col >> 11, c = col & 2047;
      const float* bp = which == 0 ? b0 : (which == 1 ? b1 : b2);
      bv = bp[c];
    } else {
      bv = b0[col];
    }
#pragma unroll
    for (int mi = 0; mi < 4; ++mi)
#pragma unroll
      for (int r = 0; r < 4; ++r) {
        const long row = bm + wgM * 64 + mi * 16 + 4 * g + r;
        const float v = acc[mi][ni][r] + bv;
        if (MODE == 4) {
          const int which = col >> 11, c = col & 2047, head = c >> 7, d = c & 127;
          if (which == 0)      O0[((long)head * SEQ + row) * HD + d] = f2bu(v * QSCALE_L2E);
          else if (which == 1) O1[((long)head * SEQ + row) * HD + d] = f2bu(v);
          else                 O2[((long)head * HD + d) * SEQ + row] = f2bu(v);
        } else {
          Of[row * (long)N + col] = v;
        }
      }
  }
#undef STAGE
#undef QUADD
}

// ---------------- flash attention v5 ----------------------------------------
// R8/R11-verified structure; Po partials bf16 (halves partial traffic).
#define KVB 64
__global__ __launch_bounds__(256) void flash_attn(
    const unsigned short* __restrict__ Qb,
    const unsigned short* __restrict__ Kb,
    const unsigned short* __restrict__ VTb,
    unsigned short* __restrict__ Po,         // [NH][32][2][64][128] bf16
    float* __restrict__ Pl)                  // [NH][32][2][64] f32
{
  __shared__ __align__(16) unsigned short Kt[64 * 128];
  __shared__ __align__(16) unsigned short Vt[128 * 64];
  __shared__ __align__(16) unsigned short Pt[4][16 * 64];
  const int tid = threadIdx.x;
  const int l = tid & 63, w = tid >> 6;
  const int g = l >> 4, q = l & 15;
  const int h = blockIdx.y, qb = blockIdx.x, half = blockIdx.z;
  const int qrow0 = qb * 64 + w * 16;

  short8 qf[4];
#pragma unroll
  for (int dc = 0; dc < 4; ++dc)
    qf[dc] = *(const short8*)&Qb[((long)h * SEQ + qrow0 + q) * HD + dc * 32 + g * 8];

  f32x4 oacc[8] = {};
  float lsum[4] = {0.f, 0.f, 0.f, 0.f};

  const int kr = tid >> 4, kc16 = tid & 15;
  const int vr = tid >> 3, vc8 = tid & 7;
  const unsigned short* Kg = Kb + (long)h * SEQ * HD + (long)half * 1024 * HD;
  const unsigned short* Vg = VTb + (long)h * HD * SEQ + half * 1024;

  short8 kreg[4], vreg[4];
#pragma unroll
  for (int it = 0; it < 4; ++it) {
    kreg[it] = *(const short8*)&Kg[(long)(kr + it * 16) * HD + kc16 * 8];
    vreg[it] = *(const short8*)&Vg[(long)(vr + it * 32) * SEQ + vc8 * 8];
  }

  for (int kb = 0; kb < 1024; kb += KVB) {
    __syncthreads();
#pragma unroll
    for (int it = 0; it < 4; ++it) {
      const int krow = kr + it * 16;
      *(short8*)&Kt[((krow * 256 + kc16 * 16) ^ ((krow & 7) << 4)) >> 1] = kreg[it];
      const int vrow = vr + it * 32;
      *(short8*)&Vt[((vrow * 128 + vc8 * 16) ^ ((vrow & 7) << 4)) >> 1] = vreg[it];
    }
    __syncthreads();
    if (kb + KVB < 1024) {
#pragma unroll
      for (int it = 0; it < 4; ++it) {
        kreg[it] = *(const short8*)&Kg[(long)(kb + KVB + kr + it * 16) * HD + kc16 * 8];
        vreg[it] = *(const short8*)&Vg[(long)(vr + it * 32) * SEQ + kb + KVB + vc8 * 8];
      }
    }

    f32x4 sacc[4] = {};
#pragma unroll
    for (int kc = 0; kc < 4; ++kc) {
      const int krow = kc * 16 + q;
      const int sw = (krow & 7) << 4;
#pragma unroll
      for (int dc = 0; dc < 4; ++dc) {
        short8 kf = *(const short8*)&Kt[((krow * 256 + dc * 64 + g * 16) ^ sw) >> 1];
        sacc[kc] = __builtin_amdgcn_mfma_f32_16x16x32_bf16(qf[dc], kf, sacc[kc], 0, 0, 0);
      }
    }

    float p[4][4];
#pragma unroll
    for (int r = 0; r < 4; ++r) {
#pragma unroll
      for (int kc = 0; kc < 4; ++kc) p[kc][r] = exp2fast(sacc[kc][r]);
      lsum[r] += (p[0][r] + p[1][r]) + (p[2][r] + p[3][r]);
    }

    unsigned short* Pw = &Pt[w][0];
#pragma unroll
    for (int r = 0; r < 4; ++r) {
      const int prow = 4 * g + r;
      const int sw = (prow & 7) << 4;
#pragma unroll
      for (int kc = 0; kc < 4; ++kc)
        Pw[((prow * 128 + (kc * 16 + q) * 2) ^ sw) >> 1] = f2bu_fast(p[kc][r]);
    }

    short8 pf[2];
    const int psw = (q & 7) << 4;
#pragma unroll
    for (int ks = 0; ks < 2; ++ks)
      pf[ks] = *(const short8*)&Pw[((q * 128 + ks * 64 + g * 16) ^ psw) >> 1];
#pragma unroll
    for (int dt = 0; dt < 8; ++dt) {
      const int vrow = dt * 16 + q;
#pragma unroll
      for (int ks = 0; ks < 2; ++ks) {
        short8 vf = *(const short8*)&Vt[((vrow * 128 + ks * 64 + g * 16) ^ psw) >> 1];
        oacc[dt] = __builtin_amdgcn_mfma_f32_16x16x32_bf16(pf[ks], vf, oacc[dt], 0, 0, 0);
      }
    }
  }

#pragma unroll
  for (int off = 1; off < 16; off <<= 1)
#pragma unroll
    for (int r = 0; r < 4; ++r) lsum[r] += __shfl_xor(lsum[r], off);

  const long tI = ((long)h * 32 + qb) * 2 + half;
  unsigned short* PoT = Po + tI * 8192;
#pragma unroll
  for (int dt = 0; dt < 8; ++dt)
#pragma unroll
    for (int r = 0; r < 4; ++r)
      PoT[(w * 16 + 4 * g + r) * 128 + dt * 16 + q] = f2bu_fast(oacc[dt][r]);
  if (q == 0) {
#pragma unroll
    for (int r = 0; r < 4; ++r)
      Pl[tI * 64 + w * 16 + 4 * g + r] = lsum[r];
  }
}

// ---------------- combine bf16 partials -> Attn bf16 ------------------------
__global__ __launch_bounds__(256) void combine_kernel(
    const unsigned short* __restrict__ Po, const float* __restrict__ Pl,
    unsigned short* __restrict__ attnb)
{
  const int qb = blockIdx.x, h = blockIdx.y;
  const long tI = ((long)h * 32 + qb) * 2;
  const unsigned short* A0 = Po + tI * 8192;
  const unsigned short* A1 = Po + (tI + 1) * 8192;
  const float* L0 = Pl + tI * 64;
  const float* L1 = Pl + (tI + 1) * 64;
  const int tid = threadIdx.x;
#pragma unroll
  for (int k = 0; k < 8; ++k) {
    const int i = tid + k * 256;          // us4 group within [64][32]
    const int row = i >> 5, c4 = i & 31;
    const us4 a = *(const us4*)&A0[i * 4];
    const us4 b = *(const us4*)&A1[i * 4];
    const float rl = 1.f / (L0[row] + L1[row]);
    us4 o;
    o[0] = f2bu((b2f(a[0]) + b2f(b[0])) * rl);
    o[1] = f2bu((b2f(a[1]) + b2f(b[1])) * rl);
    o[2] = f2bu((b2f(a[2]) + b2f(b[2])) * rl);
    o[3] = f2bu((b2f(a[3]) + b2f(b[3])) * rl);
    *(us4*)&attnb[(long)(qb * 64 + row) * HID + h * HD + c4 * 4] = o;
  }
}

extern "C" void kernel_launch(void* const* d_in, const int* in_sizes, int n_in,
                              void* d_out, int out_size, void* d_ws, size_t ws_size,
                              hipStream_t stream)
{
  const float* x  = (const float*)d_in[0];
  const float* wq = (const float*)d_in[1];
  const float* bq = (const float*)d_in[2];
  const float* wk = (const float*)d_in[3];
  const float* bk = (const float*)d_in[4];
  const float* wv = (const float*)d_in[5];
  const float* bv = (const float*)d_in[6];
  const float* wo = (const float*)d_in[7];
  const float* bo = (const float*)d_in[8];

  const long NEL = (long)HID * HID;
  unsigned short* Xb   = (unsigned short*)d_ws;
  unsigned short* Wqkv = Xb + NEL;
  unsigned short* Wob  = Wqkv + 3 * NEL;
  unsigned short* Qbuf = Wob + NEL;
  unsigned short* Kbuf = Qbuf + NEL;
  unsigned short* VTb  = Kbuf + NEL;
  unsigned short* Attn = VTb + NEL;

  // Po (16.8MB bf16) overlays [Xb, Xb+2*NEL) — dead after QKV GEMM.
  // Pl (256KB f32) lives at the start of d_out — fully overwritten by out-proj.
  unsigned short* Po = (unsigned short*)d_ws;
  float* Pl = (float*)d_out;

  // one-time opt-in for 64 KiB dynamic LDS (host-side, graph-capture safe)
  static bool attrDone = false;
  if (!attrDone) {
    hipFuncSetAttribute(reinterpret_cast<const void*>(gemm128sq<4>),
                        hipFuncAttributeMaxDynamicSharedMemorySize, 65536);
    hipFuncSetAttribute(reinterpret_cast<const void*>(gemm128sq<3>),
                        hipFuncAttributeMaxDynamicSharedMemorySize, 65536);
    attrDone = true;
  }

  cvt_kernel<<<dim3(512, 5), 256, 0, stream>>>(
      x, wq, wk, wv, wo, Xb, Wqkv, Wqkv + NEL, Wqkv + 2 * NEL, Wob, (int)NEL);

  gemm128sq<4><<<dim3(48, 16), 256, 65536, stream>>>(
      Xb, Wqkv, bq, bk, bv, Qbuf, Kbuf, VTb, nullptr, SEQ, 3 * HID, HID);

  flash_attn<<<dim3(SEQ / 64, NH, 2), 256, 0, stream>>>(Qbuf, Kbuf, VTb, Po, Pl);

  combine_kernel<<<dim3(SEQ / 64, NH), 256, 0, stream>>>(Po, Pl, Attn);

  gemm128sq<3><<<dim3(16, 16), 256, 65536, stream>>>(
      Attn, Wob, bo, nullptr, nullptr, nullptr, nullptr, nullptr,
      (float*)d_out, SEQ, HID, HID);
}

// Round 3
// 176.432 us; speedup vs baseline: 1.0934x; 1.0515x over previous
//
#include <hip/hip_runtime.h>
#include <hip/hip_bf16.h>
#include <stdint.h>

#define SEQ 2048
#define HID 2048
#define NH 16
#define HD 128
// 1/sqrt(128) * log2(e): softmax runs in exp2 domain
#define QSCALE_L2E 0.1275304429019769f

typedef __attribute__((ext_vector_type(4))) float f32x4;
typedef __attribute__((ext_vector_type(8))) short short8;
typedef __attribute__((ext_vector_type(4))) float f4;
typedef __attribute__((ext_vector_type(4))) unsigned short us4;

__device__ __forceinline__ unsigned short f2bu(float f) {
  union { float f; unsigned int u; } c; c.f = f;
  unsigned int u = c.u + 0x7fffu + ((c.u >> 16) & 1u);  // RNE, finite inputs
  return (unsigned short)(u >> 16);
}

__device__ __forceinline__ unsigned short f2bu_fast(float f) {
  union { float f; unsigned int u; } c; c.f = f;
  return (unsigned short)((c.u + 0x8000u) >> 16);
}

__device__ __forceinline__ float b2f(unsigned short u) {
  union { unsigned int u; float f; } c; c.u = ((unsigned int)u) << 16; return c.f;
}

__device__ __forceinline__ float exp2fast(float x) {
  float r; asm("v_exp_f32 %0, %1" : "=v"(r) : "v"(x)); return r;
}

__device__ __forceinline__ void gload_lds16(const void* g, void* l) {
  __builtin_amdgcn_global_load_lds((const __attribute__((address_space(1))) void*)g,
                                   (__attribute__((address_space(3))) void*)l, 16, 0, 0);
}

#define BAR() __builtin_amdgcn_s_barrier()
#define LGKM0() do { asm volatile("s_waitcnt lgkmcnt(0)" ::: "memory"); __builtin_amdgcn_sched_barrier(0); } while (0)
#define VM6()   do { asm volatile("s_waitcnt vmcnt(6)"   ::: "memory"); __builtin_amdgcn_sched_barrier(0); } while (0)
#define VM0()   do { asm volatile("s_waitcnt vmcnt(0)"   ::: "memory"); __builtin_amdgcn_sched_barrier(0); } while (0)

// ---------------- fp32 -> bf16 convert, 5 equal-size arrays (32B/thread) ----
__global__ __launch_bounds__(256) void cvt_kernel(
    const float* __restrict__ s0, const float* __restrict__ s1,
    const float* __restrict__ s2, const float* __restrict__ s3,
    const float* __restrict__ s4,
    unsigned short* __restrict__ d0, unsigned short* __restrict__ d1,
    unsigned short* __restrict__ d2, unsigned short* __restrict__ d3,
    unsigned short* __restrict__ d4, int n)
{
  const float* s; unsigned short* d;
  switch (blockIdx.y) {
    case 0: s = s0; d = d0; break;
    case 1: s = s1; d = d1; break;
    case 2: s = s2; d = d2; break;
    case 3: s = s3; d = d3; break;
    default: s = s4; d = d4; break;
  }
  const int stride = gridDim.x * blockDim.x;
  for (int i = blockIdx.x * blockDim.x + threadIdx.x; i * 8 < n; i += stride) {
    f4 v0 = *(const f4*)&s[i * 8];
    f4 v1 = *(const f4*)&s[i * 8 + 4];
    short8 o;
    o[0] = (short)f2bu(v0[0]); o[1] = (short)f2bu(v0[1]);
    o[2] = (short)f2bu(v0[2]); o[3] = (short)f2bu(v0[3]);
    o[4] = (short)f2bu(v1[0]); o[5] = (short)f2bu(v1[1]);
    o[6] = (short)f2bu(v1[2]); o[7] = (short)f2bu(v1[3]);
    *(short8*)&d[i * 8] = o;
  }
}

// ---------------- 64x128 bf16 GEMM  C = A[M,K] * B[N,K]^T + bias ------------
// BM=64, BN=128, BK=64, 4 waves (1Mx4N), dbuf 48KB LDS -> 3 blocks/CU.
// R14-verified loop (equal-best of all measured variants):
//   reads -> QUAD0 (compiler partial-lgkm interleave) -> LGKM0 -> BAR(a) ->
//   stage(j+2) -> QUAD1 -> VM6 -> BAR(b)
template<int MODE>
__global__ __launch_bounds__(256, 2) void gemm128(
    const unsigned short* __restrict__ A,
    const unsigned short* __restrict__ B,
    const float* __restrict__ b0, const float* __restrict__ b1, const float* __restrict__ b2,
    unsigned short* __restrict__ O0, unsigned short* __restrict__ O1, unsigned short* __restrict__ O2,
    float* __restrict__ Of, int M, int N, int K)
{
  constexpr int ASZ = 64 * 64;
  constexpr int BSZ = 128 * 64;

  extern __shared__ unsigned short lds[];
  const int tid = threadIdx.x;
  const int lane = tid & 63, w = tid >> 6;
  const int g = lane >> 4, q = lane & 15;
  const long bm = (long)blockIdx.y * 64, bn = (long)blockIdx.x * 128;
  const int NK = K >> 6;

  const int srl = lane >> 3;
  const int scE = ((lane & 7) ^ srl) * 8;
  const int c0 = (g ^ (q & 7)) * 8;
  const int c1 = c0 ^ 32;
  const int aB = q * 64;
  const int bB = (w * 32 + q) * 64;

  f32x4 acc[4][2] = {};
  short8 a[4][2], b[2][2];

#define STAGE_A(jj) do {                                                      \
    unsigned short* dst_ = lds + (((jj) & 1) ? ASZ : 0);                      \
    _Pragma("unroll")                                                         \
    for (int c_ = 0; c_ < 2; ++c_) {                                          \
      const long row_ = (c_ * 4 + w) * 8 + srl;                               \
      gload_lds16(&A[(bm + row_) * (long)K + (jj) * 64 + scE],                \
                  &dst_[(c_ * 4 + w) * 512]);                                 \
    }                                                                         \
  } while (0)

#define STAGE_B(jj) do {                                                      \
    unsigned short* dst_ = lds + 2 * ASZ + (((jj) & 1) ? BSZ : 0);            \
    _Pragma("unroll")                                                         \
    for (int c_ = 0; c_ < 4; ++c_) {                                          \
      const long row_ = (c_ * 4 + w) * 8 + srl;                               \
      gload_lds16(&B[(bn + row_) * (long)K + (jj) * 64 + scE],                \
                  &dst_[(c_ * 4 + w) * 512]);                                 \
    }                                                                         \
  } while (0)

#define QUAD8(ni)                                                             \
  do {                                                                        \
    __builtin_amdgcn_s_setprio(1);                                            \
    _Pragma("unroll")                                                         \
    for (int mi_ = 0; mi_ < 4; ++mi_) {                                       \
      acc[mi_][ni] = __builtin_amdgcn_mfma_f32_16x16x32_bf16(                 \
          a[mi_][0], b[ni][0], acc[mi_][ni], 0, 0, 0);                        \
      acc[mi_][ni] = __builtin_amdgcn_mfma_f32_16x16x32_bf16(                 \
          a[mi_][1], b[ni][1], acc[mi_][ni], 0, 0, 0);                        \
    }                                                                         \
    __builtin_amdgcn_s_setprio(0);                                            \
  } while (0)

  STAGE_A(0); STAGE_B(0);
  STAGE_A(1); STAGE_B(1);
  VM6();
  BAR();

  for (int j = 0; j < NK; ++j) {
    unsigned short* At = lds + ((j & 1) ? ASZ : 0);
    unsigned short* Bt = lds + 2 * ASZ + ((j & 1) ? BSZ : 0);

#pragma unroll
    for (int mi = 0; mi < 4; ++mi) {
      a[mi][0] = *(const short8*)&At[aB + mi * 1024 + c0];
      a[mi][1] = *(const short8*)&At[aB + mi * 1024 + c1];
    }
#pragma unroll
    for (int ni = 0; ni < 2; ++ni) {
      b[ni][0] = *(const short8*)&Bt[bB + ni * 1024 + c0];
      b[ni][1] = *(const short8*)&Bt[bB + ni * 1024 + c1];
    }
    QUAD8(0);
    LGKM0();
    BAR();                                  // (a)
    if (j + 2 < NK) { STAGE_A(j + 2); STAGE_B(j + 2); }
    QUAD8(1);
    if (j < NK - 2) { VM6(); } else { VM0(); }
    BAR();                                  // (b)
  }

#pragma unroll
  for (int ni = 0; ni < 2; ++ni) {
    const int col = (int)bn + w * 32 + ni * 16 + q;
    float bv;
    if (MODE == 4) {
      const int which = col >> 11, c = col & 2047;
      const float* bp = which == 0 ? b0 : (which == 1 ? b1 : b2);
      bv = bp[c];
    } else {
      bv = b0[col];
    }
#pragma unroll
    for (int mi = 0; mi < 4; ++mi)
#pragma unroll
      for (int r = 0; r < 4; ++r) {
        const long row = bm + mi * 16 + 4 * g + r;
        const float v = acc[mi][ni][r] + bv;
        if (MODE == 4) {
          const int which = col >> 11, c = col & 2047, head = c >> 7, d = c & 127;
          if (which == 0)      O0[((long)head * SEQ + row) * HD + d] = f2bu(v * QSCALE_L2E);
          else if (which == 1) O1[((long)head * SEQ + row) * HD + d] = f2bu(v);
          else                 O2[((long)head * HD + d) * SEQ + row] = f2bu(v);
        } else {
          Of[row * (long)N + col] = v;
        }
      }
  }
#undef STAGE_A
#undef STAGE_B
#undef QUAD8
}

// ---------------- flash attention v6: unsplit KV ----------------------------
// R17: each block now sweeps the FULL 2048-KV (32 tiles) for its 64 Q-rows,
// divides by lsum in-register, and writes Attn bf16 directly. Removes the
// Po (16.8MB) partial write, the Pl write, and the entire combine kernel
// (17MB read + 8.4MB write) -- ~34MB of HBM round-trip + one launch.
// f32 accumulation across all 32 tiles (vs bf16-quantized partial add) is
// strictly more accurate. Grid 32x16 = 512 blocks = 2 blocks/CU (40KB LDS).
#define KVB 64
__global__ __launch_bounds__(256) void flash_attn(
    const unsigned short* __restrict__ Qb,
    const unsigned short* __restrict__ Kb,
    const unsigned short* __restrict__ VTb,
    unsigned short* __restrict__ attnb)      // [SEQ][HID] bf16
{
  __shared__ __align__(16) unsigned short Kt[64 * 128];
  __shared__ __align__(16) unsigned short Vt[128 * 64];
  __shared__ __align__(16) unsigned short Pt[4][16 * 64];
  const int tid = threadIdx.x;
  const int l = tid & 63, w = tid >> 6;
  const int g = l >> 4, q = l & 15;
  const int h = blockIdx.y, qb = blockIdx.x;
  const int qrow0 = qb * 64 + w * 16;

  short8 qf[4];
#pragma unroll
  for (int dc = 0; dc < 4; ++dc)
    qf[dc] = *(const short8*)&Qb[((long)h * SEQ + qrow0 + q) * HD + dc * 32 + g * 8];

  f32x4 oacc[8] = {};
  float lsum[4] = {0.f, 0.f, 0.f, 0.f};

  const int kr = tid >> 4, kc16 = tid & 15;
  const int vr = tid >> 3, vc8 = tid & 7;
  const unsigned short* Kg = Kb + (long)h * SEQ * HD;
  const unsigned short* Vg = VTb + (long)h * HD * SEQ;

  short8 kreg[4], vreg[4];
#pragma unroll
  for (int it = 0; it < 4; ++it) {
    kreg[it] = *(const short8*)&Kg[(long)(kr + it * 16) * HD + kc16 * 8];
    vreg[it] = *(const short8*)&Vg[(long)(vr + it * 32) * SEQ + vc8 * 8];
  }

  for (int kb = 0; kb < SEQ; kb += KVB) {
    __syncthreads();
#pragma unroll
    for (int it = 0; it < 4; ++it) {
      const int krow = kr + it * 16;
      *(short8*)&Kt[((krow * 256 + kc16 * 16) ^ ((krow & 7) << 4)) >> 1] = kreg[it];
      const int vrow = vr + it * 32;
      *(short8*)&Vt[((vrow * 128 + vc8 * 16) ^ ((vrow & 7) << 4)) >> 1] = vreg[it];
    }
    __syncthreads();
    if (kb + KVB < SEQ) {
#pragma unroll
      for (int it = 0; it < 4; ++it) {
        kreg[it] = *(const short8*)&Kg[(long)(kb + KVB + kr + it * 16) * HD + kc16 * 8];
        vreg[it] = *(const short8*)&Vg[(long)(vr + it * 32) * SEQ + kb + KVB + vc8 * 8];
      }
    }

    f32x4 sacc[4] = {};
#pragma unroll
    for (int kc = 0; kc < 4; ++kc) {
      const int krow = kc * 16 + q;
      const int sw = (krow & 7) << 4;
#pragma unroll
      for (int dc = 0; dc < 4; ++dc) {
        short8 kf = *(const short8*)&Kt[((krow * 256 + dc * 64 + g * 16) ^ sw) >> 1];
        sacc[kc] = __builtin_amdgcn_mfma_f32_16x16x32_bf16(qf[dc], kf, sacc[kc], 0, 0, 0);
      }
    }

    float p[4][4];
#pragma unroll
    for (int r = 0; r < 4; ++r) {
#pragma unroll
      for (int kc = 0; kc < 4; ++kc) p[kc][r] = exp2fast(sacc[kc][r]);
      lsum[r] += (p[0][r] + p[1][r]) + (p[2][r] + p[3][r]);
    }

    unsigned short* Pw = &Pt[w][0];
#pragma unroll
    for (int r = 0; r < 4; ++r) {
      const int prow = 4 * g + r;
      const int sw = (prow & 7) << 4;
#pragma unroll
      for (int kc = 0; kc < 4; ++kc)
        Pw[((prow * 128 + (kc * 16 + q) * 2) ^ sw) >> 1] = f2bu_fast(p[kc][r]);
    }

    short8 pf[2];
    const int psw = (q & 7) << 4;
#pragma unroll
    for (int ks = 0; ks < 2; ++ks)
      pf[ks] = *(const short8*)&Pw[((q * 128 + ks * 64 + g * 16) ^ psw) >> 1];
#pragma unroll
    for (int dt = 0; dt < 8; ++dt) {
      const int vrow = dt * 16 + q;
#pragma unroll
      for (int ks = 0; ks < 2; ++ks) {
        short8 vf = *(const short8*)&Vt[((vrow * 128 + ks * 64 + g * 16) ^ psw) >> 1];
        oacc[dt] = __builtin_amdgcn_mfma_f32_16x16x32_bf16(pf[ks], vf, oacc[dt], 0, 0, 0);
      }
    }
  }

  // sum exp over the 16 q-lanes (KV columns live on q within each 16-lane grp)
#pragma unroll
  for (int off = 1; off < 16; off <<= 1)
#pragma unroll
    for (int r = 0; r < 4; ++r) lsum[r] += __shfl_xor(lsum[r], off);

  const float rl0 = 1.f / lsum[0], rl1 = 1.f / lsum[1];
  const float rl2 = 1.f / lsum[2], rl3 = 1.f / lsum[3];
#pragma unroll
  for (int dt = 0; dt < 8; ++dt) {
    const long colb = (long)h * HD + dt * 16 + q;
    attnb[(long)(qrow0 + 4 * g + 0) * HID + colb] = f2bu(oacc[dt][0] * rl0);
    attnb[(long)(qrow0 + 4 * g + 1) * HID + colb] = f2bu(oacc[dt][1] * rl1);
    attnb[(long)(qrow0 + 4 * g + 2) * HID + colb] = f2bu(oacc[dt][2] * rl2);
    attnb[(long)(qrow0 + 4 * g + 3) * HID + colb] = f2bu(oacc[dt][3] * rl3);
  }
}

extern "C" void kernel_launch(void* const* d_in, const int* in_sizes, int n_in,
                              void* d_out, int out_size, void* d_ws, size_t ws_size,
                              hipStream_t stream)
{
  const float* x  = (const float*)d_in[0];
  const float* wq = (const float*)d_in[1];
  const float* bq = (const float*)d_in[2];
  const float* wk = (const float*)d_in[3];
  const float* bk = (const float*)d_in[4];
  const float* wv = (const float*)d_in[5];
  const float* bv = (const float*)d_in[6];
  const float* wo = (const float*)d_in[7];
  const float* bo = (const float*)d_in[8];

  const long NEL = (long)HID * HID;
  unsigned short* Xb   = (unsigned short*)d_ws;
  unsigned short* Wqkv = Xb + NEL;
  unsigned short* Wob  = Wqkv + 3 * NEL;
  unsigned short* Qbuf = Wob + NEL;
  unsigned short* Kbuf = Qbuf + NEL;
  unsigned short* VTb  = Kbuf + NEL;
  unsigned short* Attn = VTb + NEL;

  cvt_kernel<<<dim3(512, 5), 256, 0, stream>>>(
      x, wq, wk, wv, wo, Xb, Wqkv, Wqkv + NEL, Wqkv + 2 * NEL, Wob, (int)NEL);

  gemm128<4><<<dim3(48, 32), 256, 49152, stream>>>(
      Xb, Wqkv, bq, bk, bv, Qbuf, Kbuf, VTb, nullptr, SEQ, 3 * HID, HID);

  flash_attn<<<dim3(SEQ / 64, NH), 256, 0, stream>>>(Qbuf, Kbuf, VTb, Attn);

  gemm128<3><<<dim3(16, 32), 256, 49152, stream>>>(
      Attn, Wob, bo, nullptr, nullptr, nullptr, nullptr, nullptr,
      (float*)d_out, SEQ, HID, HID);
}

// Round 4
// 165.187 us; speedup vs baseline: 1.1679x; 1.0681x over previous
//
#include <hip/hip_runtime.h>
#include <hip/hip_bf16.h>
#include <stdint.h>

#define SEQ 2048
#define HID 2048
#define NH 16
#define HD 128
// 1/sqrt(128) * log2(e): softmax runs in exp2 domain
#define QSCALE_L2E 0.1275304429019769f

typedef __attribute__((ext_vector_type(4))) float f32x4;
typedef __attribute__((ext_vector_type(8))) short short8;
typedef __attribute__((ext_vector_type(4))) float f4;
typedef __attribute__((ext_vector_type(4))) unsigned short us4;

__device__ __forceinline__ unsigned short f2bu(float f) {
  union { float f; unsigned int u; } c; c.f = f;
  unsigned int u = c.u + 0x7fffu + ((c.u >> 16) & 1u);  // RNE, finite inputs
  return (unsigned short)(u >> 16);
}

__device__ __forceinline__ unsigned short f2bu_fast(float f) {
  union { float f; unsigned int u; } c; c.f = f;
  return (unsigned short)((c.u + 0x8000u) >> 16);
}

__device__ __forceinline__ float b2f(unsigned short u) {
  union { unsigned int u; float f; } c; c.u = ((unsigned int)u) << 16; return c.f;
}

__device__ __forceinline__ float exp2fast(float x) {
  float r; asm("v_exp_f32 %0, %1" : "=v"(r) : "v"(x)); return r;
}

__device__ __forceinline__ void gload_lds16(const void* g, void* l) {
  __builtin_amdgcn_global_load_lds((const __attribute__((address_space(1))) void*)g,
                                   (__attribute__((address_space(3))) void*)l, 16, 0, 0);
}

#define BAR() __builtin_amdgcn_s_barrier()
#define LGKM0() do { asm volatile("s_waitcnt lgkmcnt(0)" ::: "memory"); __builtin_amdgcn_sched_barrier(0); } while (0)
#define VM6()   do { asm volatile("s_waitcnt vmcnt(6)"   ::: "memory"); __builtin_amdgcn_sched_barrier(0); } while (0)
#define VM0()   do { asm volatile("s_waitcnt vmcnt(0)"   ::: "memory"); __builtin_amdgcn_sched_barrier(0); } while (0)

// ---------------- fp32 -> bf16 convert, 5 equal-size arrays (32B/thread) ----
__global__ __launch_bounds__(256) void cvt_kernel(
    const float* __restrict__ s0, const float* __restrict__ s1,
    const float* __restrict__ s2, const float* __restrict__ s3,
    const float* __restrict__ s4,
    unsigned short* __restrict__ d0, unsigned short* __restrict__ d1,
    unsigned short* __restrict__ d2, unsigned short* __restrict__ d3,
    unsigned short* __restrict__ d4, int n)
{
  const float* s; unsigned short* d;
  switch (blockIdx.y) {
    case 0: s = s0; d = d0; break;
    case 1: s = s1; d = d1; break;
    case 2: s = s2; d = d2; break;
    case 3: s = s3; d = d3; break;
    default: s = s4; d = d4; break;
  }
  const int stride = gridDim.x * blockDim.x;
  for (int i = blockIdx.x * blockDim.x + threadIdx.x; i * 8 < n; i += stride) {
    f4 v0 = *(const f4*)&s[i * 8];
    f4 v1 = *(const f4*)&s[i * 8 + 4];
    short8 o;
    o[0] = (short)f2bu(v0[0]); o[1] = (short)f2bu(v0[1]);
    o[2] = (short)f2bu(v0[2]); o[3] = (short)f2bu(v0[3]);
    o[4] = (short)f2bu(v1[0]); o[5] = (short)f2bu(v1[1]);
    o[6] = (short)f2bu(v1[2]); o[7] = (short)f2bu(v1[3]);
    *(short8*)&d[i * 8] = o;
  }
}

// ---------------- 128x128 bf16 GEMM, m97-style single-buffer ----------------
// R18: BM=BN=128, BK=64, 4 waves (2Mx2N), per-wave 64x64 (acc[4][4]).
// SINGLE 32KB LDS buffer + launch_bounds(256,3) -> 3 blocks/CU. The per-tile
// vmcnt(0)+barrier drain is covered by the OTHER resident blocks (m114
// cross-block MFMA/staging overlap) instead of intra-block dbuf pipelining
// (which the lockstep barriers negated at 2 blocks/CU: 43% all-wave stall).
// Swizzle/fragment geometry identical to the R16-verified kernel.
template<int MODE>
__global__ __launch_bounds__(256, 3) void gemm97(
    const unsigned short* __restrict__ A,
    const unsigned short* __restrict__ B,
    const float* __restrict__ b0, const float* __restrict__ b1, const float* __restrict__ b2,
    unsigned short* __restrict__ O0, unsigned short* __restrict__ O1, unsigned short* __restrict__ O2,
    float* __restrict__ Of, int M, int N, int K)
{
  extern __shared__ unsigned short lds[];  // A[128*64] @0, B[128*64] @8192 el
  const int tid = threadIdx.x;
  const int lane = tid & 63, w = tid >> 6;
  const int g = lane >> 4, q = lane & 15;
  const int wgM = w >> 1, wgN = w & 1;     // 2M x 2N wave grid
  const long bm = (long)blockIdx.y * 128, bn = (long)blockIdx.x * 128;
  const int NK = K >> 6;

  // staging lane geometry (proven): lane writes LDS row (l>>3), 16B-block
  // (l&7); global column block pre-swizzled: (l&7)^(l>>3)
  const int srl = lane >> 3;
  const int scE = ((lane & 7) ^ srl) * 8;
  // fragment read swizzle: logical k-block g of row r stored at g^(r&7);
  // all frag rows have row&7 == q&7
  const int c0 = (g ^ (q & 7)) * 8;
  const int c1 = c0 ^ 32;
  const int aB = (wgM * 64 + q) * 64;
  const int bB = (wgN * 64 + q) * 64;

  f32x4 acc[4][4] = {};
  short8 a[4][2], b[4][2];

#define STAGE(gp, gbase, jj, ldsOff) do {                                     \
    _Pragma("unroll")                                                         \
    for (int c_ = 0; c_ < 4; ++c_) {                                          \
      const long row_ = (c_ * 4 + w) * 8 + srl;                               \
      gload_lds16(&(gp)[((gbase) + row_) * (long)K + (jj) * 64 + scE],        \
                  &lds[(ldsOff) + (c_ * 4 + w) * 512]);                       \
    }                                                                         \
  } while (0)

#define QUADD(n0, n1)                                                         \
  do {                                                                        \
    __builtin_amdgcn_s_setprio(1);                                            \
    _Pragma("unroll")                                                         \
    for (int mi_ = 0; mi_ < 4; ++mi_) {                                       \
      acc[mi_][n0] = __builtin_amdgcn_mfma_f32_16x16x32_bf16(                 \
          a[mi_][0], b[n0][0], acc[mi_][n0], 0, 0, 0);                        \
      acc[mi_][n0] = __builtin_amdgcn_mfma_f32_16x16x32_bf16(                 \
          a[mi_][1], b[n0][1], acc[mi_][n0], 0, 0, 0);                        \
      acc[mi_][n1] = __builtin_amdgcn_mfma_f32_16x16x32_bf16(                 \
          a[mi_][0], b[n1][0], acc[mi_][n1], 0, 0, 0);                        \
      acc[mi_][n1] = __builtin_amdgcn_mfma_f32_16x16x32_bf16(                 \
          a[mi_][1], b[n1][1], acc[mi_][n1], 0, 0, 0);                        \
    }                                                                         \
    __builtin_amdgcn_s_setprio(0);                                            \
  } while (0)

  for (int j = 0; j < NK; ++j) {
    STAGE(A, bm, j, 0);
    STAGE(B, bn, j, 8192);
    VM0();                                  // tile landed
    BAR();                                  // all waves see full tile
#pragma unroll
    for (int mi = 0; mi < 4; ++mi) {
      a[mi][0] = *(const short8*)&lds[aB + mi * 1024 + c0];
      a[mi][1] = *(const short8*)&lds[aB + mi * 1024 + c1];
    }
#pragma unroll
    for (int ni = 0; ni < 4; ++ni) {
      b[ni][0] = *(const short8*)&lds[8192 + bB + ni * 1024 + c0];
      b[ni][1] = *(const short8*)&lds[8192 + bB + ni * 1024 + c1];
    }
    QUADD(0, 1);
    QUADD(2, 3);
    BAR();                                  // all reads done -> safe to restage
  }

#pragma unroll
  for (int ni = 0; ni < 4; ++ni) {
    const int col = (int)bn + wgN * 64 + ni * 16 + q;
    float bv;
    if (MODE == 4) {
      const int which = col >> 11, c = col & 2047;
      const float* bp = which == 0 ? b0 : (which == 1 ? b1 : b2);
      bv = bp[c];
    } else {
      bv = b0[col];
    }
#pragma unroll
    for (int mi = 0; mi < 4; ++mi)
#pragma unroll
      for (int r = 0; r < 4; ++r) {
        const long row = bm + wgM * 64 + mi * 16 + 4 * g + r;
        const float v = acc[mi][ni][r] + bv;
        if (MODE == 4) {
          const int which = col >> 11, c = col & 2047, head = c >> 7, d = c & 127;
          if (which == 0)      O0[((long)head * SEQ + row) * HD + d] = f2bu(v * QSCALE_L2E);
          else if (which == 1) O1[((long)head * SEQ + row) * HD + d] = f2bu(v);
          else                 O2[((long)head * HD + d) * SEQ + row] = f2bu(v);
        } else {
          Of[row * (long)N + col] = v;
        }
      }
  }
#undef STAGE
#undef QUADD
}

// ---------------- 64x128 bf16 GEMM  C = A[M,K] * B[N,K]^T + bias ------------
// Kept for out-projection (grid 16x32 = 512 blocks; the 128^2 kernel would be
// 256 blocks = 1 block/CU -> no cross-block overlap).
template<int MODE>
__global__ __launch_bounds__(256, 2) void gemm128(
    const unsigned short* __restrict__ A,
    const unsigned short* __restrict__ B,
    const float* __restrict__ b0, const float* __restrict__ b1, const float* __restrict__ b2,
    unsigned short* __restrict__ O0, unsigned short* __restrict__ O1, unsigned short* __restrict__ O2,
    float* __restrict__ Of, int M, int N, int K)
{
  constexpr int ASZ = 64 * 64;
  constexpr int BSZ = 128 * 64;

  extern __shared__ unsigned short lds[];
  const int tid = threadIdx.x;
  const int lane = tid & 63, w = tid >> 6;
  const int g = lane >> 4, q = lane & 15;
  const long bm = (long)blockIdx.y * 64, bn = (long)blockIdx.x * 128;
  const int NK = K >> 6;

  const int srl = lane >> 3;
  const int scE = ((lane & 7) ^ srl) * 8;
  const int c0 = (g ^ (q & 7)) * 8;
  const int c1 = c0 ^ 32;
  const int aB = q * 64;
  const int bB = (w * 32 + q) * 64;

  f32x4 acc[4][2] = {};
  short8 a[4][2], b[2][2];

#define STAGE_A(jj) do {                                                      \
    unsigned short* dst_ = lds + (((jj) & 1) ? ASZ : 0);                      \
    _Pragma("unroll")                                                         \
    for (int c_ = 0; c_ < 2; ++c_) {                                          \
      const long row_ = (c_ * 4 + w) * 8 + srl;                               \
      gload_lds16(&A[(bm + row_) * (long)K + (jj) * 64 + scE],                \
                  &dst_[(c_ * 4 + w) * 512]);                                 \
    }                                                                         \
  } while (0)

#define STAGE_B(jj) do {                                                      \
    unsigned short* dst_ = lds + 2 * ASZ + (((jj) & 1) ? BSZ : 0);            \
    _Pragma("unroll")                                                         \
    for (int c_ = 0; c_ < 4; ++c_) {                                          \
      const long row_ = (c_ * 4 + w) * 8 + srl;                               \
      gload_lds16(&B[(bn + row_) * (long)K + (jj) * 64 + scE],                \
                  &dst_[(c_ * 4 + w) * 512]);                                 \
    }                                                                         \
  } while (0)

#define QUAD8(ni)                                                             \
  do {                                                                        \
    __builtin_amdgcn_s_setprio(1);                                            \
    _Pragma("unroll")                                                         \
    for (int mi_ = 0; mi_ < 4; ++mi_) {                                       \
      acc[mi_][ni] = __builtin_amdgcn_mfma_f32_16x16x32_bf16(                 \
          a[mi_][0], b[ni][0], acc[mi_][ni], 0, 0, 0);                        \
      acc[mi_][ni] = __builtin_amdgcn_mfma_f32_16x16x32_bf16(                 \
          a[mi_][1], b[ni][1], acc[mi_][ni], 0, 0, 0);                        \
    }                                                                         \
    __builtin_amdgcn_s_setprio(0);                                            \
  } while (0)

  STAGE_A(0); STAGE_B(0);
  STAGE_A(1); STAGE_B(1);
  VM6();
  BAR();

  for (int j = 0; j < NK; ++j) {
    unsigned short* At = lds + ((j & 1) ? ASZ : 0);
    unsigned short* Bt = lds + 2 * ASZ + ((j & 1) ? BSZ : 0);

#pragma unroll
    for (int mi = 0; mi < 4; ++mi) {
      a[mi][0] = *(const short8*)&At[aB + mi * 1024 + c0];
      a[mi][1] = *(const short8*)&At[aB + mi * 1024 + c1];
    }
#pragma unroll
    for (int ni = 0; ni < 2; ++ni) {
      b[ni][0] = *(const short8*)&Bt[bB + ni * 1024 + c0];
      b[ni][1] = *(const short8*)&Bt[bB + ni * 1024 + c1];
    }
    QUAD8(0);
    LGKM0();
    BAR();                                  // (a)
    if (j + 2 < NK) { STAGE_A(j + 2); STAGE_B(j + 2); }
    QUAD8(1);
    if (j < NK - 2) { VM6(); } else { VM0(); }
    BAR();                                  // (b)
  }

#pragma unroll
  for (int ni = 0; ni < 2; ++ni) {
    const int col = (int)bn + w * 32 + ni * 16 + q;
    float bv;
    if (MODE == 4) {
      const int which = col >> 11, c = col & 2047;
      const float* bp = which == 0 ? b0 : (which == 1 ? b1 : b2);
      bv = bp[c];
    } else {
      bv = b0[col];
    }
#pragma unroll
    for (int mi = 0; mi < 4; ++mi)
#pragma unroll
      for (int r = 0; r < 4; ++r) {
        const long row = bm + mi * 16 + 4 * g + r;
        const float v = acc[mi][ni][r] + bv;
        if (MODE == 4) {
          const int which = col >> 11, c = col & 2047, head = c >> 7, d = c & 127;
          if (which == 0)      O0[((long)head * SEQ + row) * HD + d] = f2bu(v * QSCALE_L2E);
          else if (which == 1) O1[((long)head * SEQ + row) * HD + d] = f2bu(v);
          else                 O2[((long)head * HD + d) * SEQ + row] = f2bu(v);
        } else {
          Of[row * (long)N + col] = v;
        }
      }
  }
#undef STAGE_A
#undef STAGE_B
#undef QUAD8
}

// ---------------- flash attention v6: unsplit KV ----------------------------
// R17-verified: each block sweeps the full 2048-KV (32 tiles) for its 64
// Q-rows, divides by lsum in-register, writes Attn bf16 directly.
#define KVB 64
__global__ __launch_bounds__(256) void flash_attn(
    const unsigned short* __restrict__ Qb,
    const unsigned short* __restrict__ Kb,
    const unsigned short* __restrict__ VTb,
    unsigned short* __restrict__ attnb)      // [SEQ][HID] bf16
{
  __shared__ __align__(16) unsigned short Kt[64 * 128];
  __shared__ __align__(16) unsigned short Vt[128 * 64];
  __shared__ __align__(16) unsigned short Pt[4][16 * 64];
  const int tid = threadIdx.x;
  const int l = tid & 63, w = tid >> 6;
  const int g = l >> 4, q = l & 15;
  const int h = blockIdx.y, qb = blockIdx.x;
  const int qrow0 = qb * 64 + w * 16;

  short8 qf[4];
#pragma unroll
  for (int dc = 0; dc < 4; ++dc)
    qf[dc] = *(const short8*)&Qb[((long)h * SEQ + qrow0 + q) * HD + dc * 32 + g * 8];

  f32x4 oacc[8] = {};
  float lsum[4] = {0.f, 0.f, 0.f, 0.f};

  const int kr = tid >> 4, kc16 = tid & 15;
  const int vr = tid >> 3, vc8 = tid & 7;
  const unsigned short* Kg = Kb + (long)h * SEQ * HD;
  const unsigned short* Vg = VTb + (long)h * HD * SEQ;

  short8 kreg[4], vreg[4];
#pragma unroll
  for (int it = 0; it < 4; ++it) {
    kreg[it] = *(const short8*)&Kg[(long)(kr + it * 16) * HD + kc16 * 8];
    vreg[it] = *(const short8*)&Vg[(long)(vr + it * 32) * SEQ + vc8 * 8];
  }

  for (int kb = 0; kb < SEQ; kb += KVB) {
    __syncthreads();
#pragma unroll
    for (int it = 0; it < 4; ++it) {
      const int krow = kr + it * 16;
      *(short8*)&Kt[((krow * 256 + kc16 * 16) ^ ((krow & 7) << 4)) >> 1] = kreg[it];
      const int vrow = vr + it * 32;
      *(short8*)&Vt[((vrow * 128 + vc8 * 16) ^ ((vrow & 7) << 4)) >> 1] = vreg[it];
    }
    __syncthreads();
    if (kb + KVB < SEQ) {
#pragma unroll
      for (int it = 0; it < 4; ++it) {
        kreg[it] = *(const short8*)&Kg[(long)(kb + KVB + kr + it * 16) * HD + kc16 * 8];
        vreg[it] = *(const short8*)&Vg[(long)(vr + it * 32) * SEQ + kb + KVB + vc8 * 8];
      }
    }

    f32x4 sacc[4] = {};
#pragma unroll
    for (int kc = 0; kc < 4; ++kc) {
      const int krow = kc * 16 + q;
      const int sw = (krow & 7) << 4;
#pragma unroll
      for (int dc = 0; dc < 4; ++dc) {
        short8 kf = *(const short8*)&Kt[((krow * 256 + dc * 64 + g * 16) ^ sw) >> 1];
        sacc[kc] = __builtin_amdgcn_mfma_f32_16x16x32_bf16(qf[dc], kf, sacc[kc], 0, 0, 0);
      }
    }

    float p[4][4];
#pragma unroll
    for (int r = 0; r < 4; ++r) {
#pragma unroll
      for (int kc = 0; kc < 4; ++kc) p[kc][r] = exp2fast(sacc[kc][r]);
      lsum[r] += (p[0][r] + p[1][r]) + (p[2][r] + p[3][r]);
    }

    unsigned short* Pw = &Pt[w][0];
#pragma unroll
    for (int r = 0; r < 4; ++r) {
      const int prow = 4 * g + r;
      const int sw = (prow & 7) << 4;
#pragma unroll
      for (int kc = 0; kc < 4; ++kc)
        Pw[((prow * 128 + (kc * 16 + q) * 2) ^ sw) >> 1] = f2bu_fast(p[kc][r]);
    }

    short8 pf[2];
    const int psw = (q & 7) << 4;
#pragma unroll
    for (int ks = 0; ks < 2; ++ks)
      pf[ks] = *(const short8*)&Pw[((q * 128 + ks * 64 + g * 16) ^ psw) >> 1];
#pragma unroll
    for (int dt = 0; dt < 8; ++dt) {
      const int vrow = dt * 16 + q;
#pragma unroll
      for (int ks = 0; ks < 2; ++ks) {
        short8 vf = *(const short8*)&Vt[((vrow * 128 + ks * 64 + g * 16) ^ psw) >> 1];
        oacc[dt] = __builtin_amdgcn_mfma_f32_16x16x32_bf16(pf[ks], vf, oacc[dt], 0, 0, 0);
      }
    }
  }

  // sum exp over the 16 q-lanes (KV columns live on q within each 16-lane grp)
#pragma unroll
  for (int off = 1; off < 16; off <<= 1)
#pragma unroll
    for (int r = 0; r < 4; ++r) lsum[r] += __shfl_xor(lsum[r], off);

  const float rl0 = 1.f / lsum[0], rl1 = 1.f / lsum[1];
  const float rl2 = 1.f / lsum[2], rl3 = 1.f / lsum[3];
#pragma unroll
  for (int dt = 0; dt < 8; ++dt) {
    const long colb = (long)h * HD + dt * 16 + q;
    attnb[(long)(qrow0 + 4 * g + 0) * HID + colb] = f2bu(oacc[dt][0] * rl0);
    attnb[(long)(qrow0 + 4 * g + 1) * HID + colb] = f2bu(oacc[dt][1] * rl1);
    attnb[(long)(qrow0 + 4 * g + 2) * HID + colb] = f2bu(oacc[dt][2] * rl2);
    attnb[(long)(qrow0 + 4 * g + 3) * HID + colb] = f2bu(oacc[dt][3] * rl3);
  }
}

extern "C" void kernel_launch(void* const* d_in, const int* in_sizes, int n_in,
                              void* d_out, int out_size, void* d_ws, size_t ws_size,
                              hipStream_t stream)
{
  const float* x  = (const float*)d_in[0];
  const float* wq = (const float*)d_in[1];
  const float* bq = (const float*)d_in[2];
  const float* wk = (const float*)d_in[3];
  const float* bk = (const float*)d_in[4];
  const float* wv = (const float*)d_in[5];
  const float* bv = (const float*)d_in[6];
  const float* wo = (const float*)d_in[7];
  const float* bo = (const float*)d_in[8];

  const long NEL = (long)HID * HID;
  unsigned short* Xb   = (unsigned short*)d_ws;
  unsigned short* Wqkv = Xb + NEL;
  unsigned short* Wob  = Wqkv + 3 * NEL;
  unsigned short* Qbuf = Wob + NEL;
  unsigned short* Kbuf = Qbuf + NEL;
  unsigned short* VTb  = Kbuf + NEL;
  unsigned short* Attn = VTb + NEL;

  cvt_kernel<<<dim3(512, 5), 256, 0, stream>>>(
      x, wq, wk, wv, wo, Xb, Wqkv, Wqkv + NEL, Wqkv + 2 * NEL, Wob, (int)NEL);

  gemm97<4><<<dim3(48, 16), 256, 32768, stream>>>(
      Xb, Wqkv, bq, bk, bv, Qbuf, Kbuf, VTb, nullptr, SEQ, 3 * HID, HID);

  flash_attn<<<dim3(SEQ / 64, NH), 256, 0, stream>>>(Qbuf, Kbuf, VTb, Attn);

  gemm128<3><<<dim3(16, 32), 256, 49152, stream>>>(
      Attn, Wob, bo, nullptr, nullptr, nullptr, nullptr, nullptr,
      (float*)d_out, SEQ, HID, HID);
}

// Round 5
// 162.950 us; speedup vs baseline: 1.1839x; 1.0137x over previous
//
#include <hip/hip_runtime.h>
#include <hip/hip_bf16.h>
#include <stdint.h>

#define SEQ 2048
#define HID 2048
#define NH 16
#define HD 128
// 1/sqrt(128) * log2(e): softmax runs in exp2 domain
#define QSCALE_L2E 0.1275304429019769f

typedef __attribute__((ext_vector_type(4))) float f32x4;
typedef __attribute__((ext_vector_type(8))) short short8;
typedef __attribute__((ext_vector_type(4))) float f4;
typedef __attribute__((ext_vector_type(4))) unsigned short us4;

__device__ __forceinline__ unsigned short f2bu(float f) {
  union { float f; unsigned int u; } c; c.f = f;
  unsigned int u = c.u + 0x7fffu + ((c.u >> 16) & 1u);  // RNE, finite inputs
  return (unsigned short)(u >> 16);
}

__device__ __forceinline__ unsigned short f2bu_fast(float f) {
  union { float f; unsigned int u; } c; c.f = f;
  return (unsigned short)((c.u + 0x8000u) >> 16);
}

__device__ __forceinline__ float b2f(unsigned short u) {
  union { unsigned int u; float f; } c; c.u = ((unsigned int)u) << 16; return c.f;
}

__device__ __forceinline__ float exp2fast(float x) {
  float r; asm("v_exp_f32 %0, %1" : "=v"(r) : "v"(x)); return r;
}

__device__ __forceinline__ void gload_lds16(const void* g, void* l) {
  __builtin_amdgcn_global_load_lds((const __attribute__((address_space(1))) void*)g,
                                   (__attribute__((address_space(3))) void*)l, 16, 0, 0);
}

#define BAR() __builtin_amdgcn_s_barrier()
#define LGKM0() do { asm volatile("s_waitcnt lgkmcnt(0)" ::: "memory"); __builtin_amdgcn_sched_barrier(0); } while (0)
#define VM6()   do { asm volatile("s_waitcnt vmcnt(6)"   ::: "memory"); __builtin_amdgcn_sched_barrier(0); } while (0)
#define VM0()   do { asm volatile("s_waitcnt vmcnt(0)"   ::: "memory"); __builtin_amdgcn_sched_barrier(0); } while (0)

// ---------------- fp32 -> bf16 convert, 5 equal-size arrays (32B/thread) ----
__global__ __launch_bounds__(256) void cvt_kernel(
    const float* __restrict__ s0, const float* __restrict__ s1,
    const float* __restrict__ s2, const float* __restrict__ s3,
    const float* __restrict__ s4,
    unsigned short* __restrict__ d0, unsigned short* __restrict__ d1,
    unsigned short* __restrict__ d2, unsigned short* __restrict__ d3,
    unsigned short* __restrict__ d4, int n)
{
  const float* s; unsigned short* d;
  switch (blockIdx.y) {
    case 0: s = s0; d = d0; break;
    case 1: s = s1; d = d1; break;
    case 2: s = s2; d = d2; break;
    case 3: s = s3; d = d3; break;
    default: s = s4; d = d4; break;
  }
  const int stride = gridDim.x * blockDim.x;
  for (int i = blockIdx.x * blockDim.x + threadIdx.x; i * 8 < n; i += stride) {
    f4 v0 = *(const f4*)&s[i * 8];
    f4 v1 = *(const f4*)&s[i * 8 + 4];
    short8 o;
    o[0] = (short)f2bu(v0[0]); o[1] = (short)f2bu(v0[1]);
    o[2] = (short)f2bu(v0[2]); o[3] = (short)f2bu(v0[3]);
    o[4] = (short)f2bu(v1[0]); o[5] = (short)f2bu(v1[1]);
    o[6] = (short)f2bu(v1[2]); o[7] = (short)f2bu(v1[3]);
    *(short8*)&d[i * 8] = o;
  }
}

// ---------------- 128x128 bf16 GEMM, m97-style single-buffer ----------------
// R18-verified WIN (QKV 77 -> ~50us): BM=BN=128, BK=64, 4 waves (2Mx2N),
// per-wave 64x64 (acc[4][4]). SINGLE 32KB LDS buffer + launch_bounds(256,3)
// -> 3 blocks/CU; the per-tile vmcnt(0)+barrier drain is covered by the
// OTHER resident blocks (m114 cross-block MFMA/staging overlap).
template<int MODE>
__global__ __launch_bounds__(256, 3) void gemm97(
    const unsigned short* __restrict__ A,
    const unsigned short* __restrict__ B,
    const float* __restrict__ b0, const float* __restrict__ b1, const float* __restrict__ b2,
    unsigned short* __restrict__ O0, unsigned short* __restrict__ O1, unsigned short* __restrict__ O2,
    float* __restrict__ Of, int M, int N, int K)
{
  extern __shared__ unsigned short lds[];  // A[128*64] @0, B[128*64] @8192 el
  const int tid = threadIdx.x;
  const int lane = tid & 63, w = tid >> 6;
  const int g = lane >> 4, q = lane & 15;
  const int wgM = w >> 1, wgN = w & 1;     // 2M x 2N wave grid
  const long bm = (long)blockIdx.y * 128, bn = (long)blockIdx.x * 128;
  const int NK = K >> 6;

  // staging lane geometry (proven): lane writes LDS row (l>>3), 16B-block
  // (l&7); global column block pre-swizzled: (l&7)^(l>>3)
  const int srl = lane >> 3;
  const int scE = ((lane & 7) ^ srl) * 8;
  // fragment read swizzle: logical k-block g of row r stored at g^(r&7);
  // all frag rows have row&7 == q&7
  const int c0 = (g ^ (q & 7)) * 8;
  const int c1 = c0 ^ 32;
  const int aB = (wgM * 64 + q) * 64;
  const int bB = (wgN * 64 + q) * 64;

  f32x4 acc[4][4] = {};
  short8 a[4][2], b[4][2];

#define STAGE(gp, gbase, jj, ldsOff) do {                                     \
    _Pragma("unroll")                                                         \
    for (int c_ = 0; c_ < 4; ++c_) {                                          \
      const long row_ = (c_ * 4 + w) * 8 + srl;                               \
      gload_lds16(&(gp)[((gbase) + row_) * (long)K + (jj) * 64 + scE],        \
                  &lds[(ldsOff) + (c_ * 4 + w) * 512]);                       \
    }                                                                         \
  } while (0)

#define QUADD(n0, n1)                                                         \
  do {                                                                        \
    __builtin_amdgcn_s_setprio(1);                                            \
    _Pragma("unroll")                                                         \
    for (int mi_ = 0; mi_ < 4; ++mi_) {                                       \
      acc[mi_][n0] = __builtin_amdgcn_mfma_f32_16x16x32_bf16(                 \
          a[mi_][0], b[n0][0], acc[mi_][n0], 0, 0, 0);                        \
      acc[mi_][n0] = __builtin_amdgcn_mfma_f32_16x16x32_bf16(                 \
          a[mi_][1], b[n0][1], acc[mi_][n0], 0, 0, 0);                        \
      acc[mi_][n1] = __builtin_amdgcn_mfma_f32_16x16x32_bf16(                 \
          a[mi_][0], b[n1][0], acc[mi_][n1], 0, 0, 0);                        \
      acc[mi_][n1] = __builtin_amdgcn_mfma_f32_16x16x32_bf16(                 \
          a[mi_][1], b[n1][1], acc[mi_][n1], 0, 0, 0);                        \
    }                                                                         \
    __builtin_amdgcn_s_setprio(0);                                            \
  } while (0)

  for (int j = 0; j < NK; ++j) {
    STAGE(A, bm, j, 0);
    STAGE(B, bn, j, 8192);
    VM0();                                  // tile landed
    BAR();                                  // all waves see full tile
#pragma unroll
    for (int mi = 0; mi < 4; ++mi) {
      a[mi][0] = *(const short8*)&lds[aB + mi * 1024 + c0];
      a[mi][1] = *(const short8*)&lds[aB + mi * 1024 + c1];
    }
#pragma unroll
    for (int ni = 0; ni < 4; ++ni) {
      b[ni][0] = *(const short8*)&lds[8192 + bB + ni * 1024 + c0];
      b[ni][1] = *(const short8*)&lds[8192 + bB + ni * 1024 + c1];
    }
    QUADD(0, 1);
    QUADD(2, 3);
    BAR();                                  // all reads done -> safe to restage
  }

#pragma unroll
  for (int ni = 0; ni < 4; ++ni) {
    const int col = (int)bn + wgN * 64 + ni * 16 + q;
    float bv;
    if (MODE == 4) {
      const int which = col >> 11, c = col & 2047;
      const float* bp = which == 0 ? b0 : (which == 1 ? b1 : b2);
      bv = bp[c];
    } else {
      bv = b0[col];
    }
#pragma unroll
    for (int mi = 0; mi < 4; ++mi)
#pragma unroll
      for (int r = 0; r < 4; ++r) {
        const long row = bm + wgM * 64 + mi * 16 + 4 * g + r;
        const float v = acc[mi][ni][r] + bv;
        if (MODE == 4) {
          const int which = col >> 11, c = col & 2047, head = c >> 7, d = c & 127;
          if (which == 0)      O0[((long)head * SEQ + row) * HD + d] = f2bu(v * QSCALE_L2E);
          else if (which == 1) O1[((long)head * SEQ + row) * HD + d] = f2bu(v);
          else                 O2[((long)head * HD + d) * SEQ + row] = f2bu(v);
        } else {
          Of[row * (long)N + col] = v;
        }
      }
  }
#undef STAGE
#undef QUADD
}

// ---------------- 64x128 bf16 GEMM  C = A[M,K] * B[N,K]^T + bias ------------
// Kept for out-projection (grid 16x32 = 512 blocks; the 128^2 kernel would be
// 256 blocks = 1 block/CU -> no cross-block overlap).
template<int MODE>
__global__ __launch_bounds__(256, 2) void gemm128(
    const unsigned short* __restrict__ A,
    const unsigned short* __restrict__ B,
    const float* __restrict__ b0, const float* __restrict__ b1, const float* __restrict__ b2,
    unsigned short* __restrict__ O0, unsigned short* __restrict__ O1, unsigned short* __restrict__ O2,
    float* __restrict__ Of, int M, int N, int K)
{
  constexpr int ASZ = 64 * 64;
  constexpr int BSZ = 128 * 64;

  extern __shared__ unsigned short lds[];
  const int tid = threadIdx.x;
  const int lane = tid & 63, w = tid >> 6;
  const int g = lane >> 4, q = lane & 15;
  const long bm = (long)blockIdx.y * 64, bn = (long)blockIdx.x * 128;
  const int NK = K >> 6;

  const int srl = lane >> 3;
  const int scE = ((lane & 7) ^ srl) * 8;
  const int c0 = (g ^ (q & 7)) * 8;
  const int c1 = c0 ^ 32;
  const int aB = q * 64;
  const int bB = (w * 32 + q) * 64;

  f32x4 acc[4][2] = {};
  short8 a[4][2], b[2][2];

#define STAGE_A(jj) do {                                                      \
    unsigned short* dst_ = lds + (((jj) & 1) ? ASZ : 0);                      \
    _Pragma("unroll")                                                         \
    for (int c_ = 0; c_ < 2; ++c_) {                                          \
      const long row_ = (c_ * 4 + w) * 8 + srl;                               \
      gload_lds16(&A[(bm + row_) * (long)K + (jj) * 64 + scE],                \
                  &dst_[(c_ * 4 + w) * 512]);                                 \
    }                                                                         \
  } while (0)

#define STAGE_B(jj) do {                                                      \
    unsigned short* dst_ = lds + 2 * ASZ + (((jj) & 1) ? BSZ : 0);            \
    _Pragma("unroll")                                                         \
    for (int c_ = 0; c_ < 4; ++c_) {                                          \
      const long row_ = (c_ * 4 + w) * 8 + srl;                               \
      gload_lds16(&B[(bn + row_) * (long)K + (jj) * 64 + scE],                \
                  &dst_[(c_ * 4 + w) * 512]);                                 \
    }                                                                         \
  } while (0)

#define QUAD8(ni)                                                             \
  do {                                                                        \
    __builtin_amdgcn_s_setprio(1);                                            \
    _Pragma("unroll")                                                         \
    for (int mi_ = 0; mi_ < 4; ++mi_) {                                       \
      acc[mi_][ni] = __builtin_amdgcn_mfma_f32_16x16x32_bf16(                 \
          a[mi_][0], b[ni][0], acc[mi_][ni], 0, 0, 0);                        \
      acc[mi_][ni] = __builtin_amdgcn_mfma_f32_16x16x32_bf16(                 \
          a[mi_][1], b[ni][1], acc[mi_][ni], 0, 0, 0);                        \
    }                                                                         \
    __builtin_amdgcn_s_setprio(0);                                            \
  } while (0)

  STAGE_A(0); STAGE_B(0);
  STAGE_A(1); STAGE_B(1);
  VM6();
  BAR();

  for (int j = 0; j < NK; ++j) {
    unsigned short* At = lds + ((j & 1) ? ASZ : 0);
    unsigned short* Bt = lds + 2 * ASZ + ((j & 1) ? BSZ : 0);

#pragma unroll
    for (int mi = 0; mi < 4; ++mi) {
      a[mi][0] = *(const short8*)&At[aB + mi * 1024 + c0];
      a[mi][1] = *(const short8*)&At[aB + mi * 1024 + c1];
    }
#pragma unroll
    for (int ni = 0; ni < 2; ++ni) {
      b[ni][0] = *(const short8*)&Bt[bB + ni * 1024 + c0];
      b[ni][1] = *(const short8*)&Bt[bB + ni * 1024 + c1];
    }
    QUAD8(0);
    LGKM0();
    BAR();                                  // (a)
    if (j + 2 < NK) { STAGE_A(j + 2); STAGE_B(j + 2); }
    QUAD8(1);
    if (j < NK - 2) { VM6(); } else { VM0(); }
    BAR();                                  // (b)
  }

#pragma unroll
  for (int ni = 0; ni < 2; ++ni) {
    const int col = (int)bn + w * 32 + ni * 16 + q;
    float bv;
    if (MODE == 4) {
      const int which = col >> 11, c = col & 2047;
      const float* bp = which == 0 ? b0 : (which == 1 ? b1 : b2);
      bv = bp[c];
    } else {
      bv = b0[col];
    }
#pragma unroll
    for (int mi = 0; mi < 4; ++mi)
#pragma unroll
      for (int r = 0; r < 4; ++r) {
        const long row = bm + mi * 16 + 4 * g + r;
        const float v = acc[mi][ni][r] + bv;
        if (MODE == 4) {
          const int which = col >> 11, c = col & 2047, head = c >> 7, d = c & 127;
          if (which == 0)      O0[((long)head * SEQ + row) * HD + d] = f2bu(v * QSCALE_L2E);
          else if (which == 1) O1[((long)head * SEQ + row) * HD + d] = f2bu(v);
          else                 O2[((long)head * HD + d) * SEQ + row] = f2bu(v);
        } else {
          Of[row * (long)N + col] = v;
        }
      }
  }
#undef STAGE_A
#undef STAGE_B
#undef QUAD8
}

// ---------------- flash attention v7: unsplit KV + XCD swizzle + setprio ----
// R19: 1D grid 512, decoded so each XCD owns 2 COMPLETE heads (2MB KV fits
// the 4MB per-XCD L2): xcd = bid&7, h = (bid&7)*2 + ((bid>>3)>>5),
// qb = (bid>>3)&31. Bijective (512 % 8 == 0). Removes the ~2.8x KV HBM
// re-fetch (FETCH 69.7MB -> ~25MB) and turns ~900cy HBM misses into ~200cy
// L2 hits for this latency-bound kernel. setprio(1) around both MFMA
// clusters (independent-block regime: m191 attn +4-7%).
#define KVB 64
__global__ __launch_bounds__(256) void flash_attn(
    const unsigned short* __restrict__ Qb,
    const unsigned short* __restrict__ Kb,
    const unsigned short* __restrict__ VTb,
    unsigned short* __restrict__ attnb)      // [SEQ][HID] bf16
{
  __shared__ __align__(16) unsigned short Kt[64 * 128];
  __shared__ __align__(16) unsigned short Vt[128 * 64];
  __shared__ __align__(16) unsigned short Pt[4][16 * 64];
  const int tid = threadIdx.x;
  const int l = tid & 63, w = tid >> 6;
  const int g = l >> 4, q = l & 15;
  const int bid = blockIdx.x;
  const int jj = bid >> 3;
  const int h = ((bid & 7) << 1) | (jj >> 5);   // 2 heads per XCD
  const int qb = jj & 31;
  const int qrow0 = qb * 64 + w * 16;

  short8 qf[4];
#pragma unroll
  for (int dc = 0; dc < 4; ++dc)
    qf[dc] = *(const short8*)&Qb[((long)h * SEQ + qrow0 + q) * HD + dc * 32 + g * 8];

  f32x4 oacc[8] = {};
  float lsum[4] = {0.f, 0.f, 0.f, 0.f};

  const int kr = tid >> 4, kc16 = tid & 15;
  const int vr = tid >> 3, vc8 = tid & 7;
  const unsigned short* Kg = Kb + (long)h * SEQ * HD;
  const unsigned short* Vg = VTb + (long)h * HD * SEQ;

  short8 kreg[4], vreg[4];
#pragma unroll
  for (int it = 0; it < 4; ++it) {
    kreg[it] = *(const short8*)&Kg[(long)(kr + it * 16) * HD + kc16 * 8];
    vreg[it] = *(const short8*)&Vg[(long)(vr + it * 32) * SEQ + vc8 * 8];
  }

  for (int kb = 0; kb < SEQ; kb += KVB) {
    __syncthreads();
#pragma unroll
    for (int it = 0; it < 4; ++it) {
      const int krow = kr + it * 16;
      *(short8*)&Kt[((krow * 256 + kc16 * 16) ^ ((krow & 7) << 4)) >> 1] = kreg[it];
      const int vrow = vr + it * 32;
      *(short8*)&Vt[((vrow * 128 + vc8 * 16) ^ ((vrow & 7) << 4)) >> 1] = vreg[it];
    }
    __syncthreads();
    if (kb + KVB < SEQ) {
#pragma unroll
      for (int it = 0; it < 4; ++it) {
        kreg[it] = *(const short8*)&Kg[(long)(kb + KVB + kr + it * 16) * HD + kc16 * 8];
        vreg[it] = *(const short8*)&Vg[(long)(vr + it * 32) * SEQ + kb + KVB + vc8 * 8];
      }
    }

    f32x4 sacc[4] = {};
    __builtin_amdgcn_s_setprio(1);
#pragma unroll
    for (int kc = 0; kc < 4; ++kc) {
      const int krow = kc * 16 + q;
      const int sw = (krow & 7) << 4;
#pragma unroll
      for (int dc = 0; dc < 4; ++dc) {
        short8 kf = *(const short8*)&Kt[((krow * 256 + dc * 64 + g * 16) ^ sw) >> 1];
        sacc[kc] = __builtin_amdgcn_mfma_f32_16x16x32_bf16(qf[dc], kf, sacc[kc], 0, 0, 0);
      }
    }
    __builtin_amdgcn_s_setprio(0);

    float p[4][4];
#pragma unroll
    for (int r = 0; r < 4; ++r) {
#pragma unroll
      for (int kc = 0; kc < 4; ++kc) p[kc][r] = exp2fast(sacc[kc][r]);
      lsum[r] += (p[0][r] + p[1][r]) + (p[2][r] + p[3][r]);
    }

    unsigned short* Pw = &Pt[w][0];
#pragma unroll
    for (int r = 0; r < 4; ++r) {
      const int prow = 4 * g + r;
      const int sw = (prow & 7) << 4;
#pragma unroll
      for (int kc = 0; kc < 4; ++kc)
        Pw[((prow * 128 + (kc * 16 + q) * 2) ^ sw) >> 1] = f2bu_fast(p[kc][r]);
    }

    short8 pf[2];
    const int psw = (q & 7) << 4;
#pragma unroll
    for (int ks = 0; ks < 2; ++ks)
      pf[ks] = *(const short8*)&Pw[((q * 128 + ks * 64 + g * 16) ^ psw) >> 1];
    __builtin_amdgcn_s_setprio(1);
#pragma unroll
    for (int dt = 0; dt < 8; ++dt) {
      const int vrow = dt * 16 + q;
#pragma unroll
      for (int ks = 0; ks < 2; ++ks) {
        short8 vf = *(const short8*)&Vt[((vrow * 128 + ks * 64 + g * 16) ^ psw) >> 1];
        oacc[dt] = __builtin_amdgcn_mfma_f32_16x16x32_bf16(pf[ks], vf, oacc[dt], 0, 0, 0);
      }
    }
    __builtin_amdgcn_s_setprio(0);
  }

  // sum exp over the 16 q-lanes (KV columns live on q within each 16-lane grp)
#pragma unroll
  for (int off = 1; off < 16; off <<= 1)
#pragma unroll
    for (int r = 0; r < 4; ++r) lsum[r] += __shfl_xor(lsum[r], off);

  const float rl0 = 1.f / lsum[0], rl1 = 1.f / lsum[1];
  const float rl2 = 1.f / lsum[2], rl3 = 1.f / lsum[3];
#pragma unroll
  for (int dt = 0; dt < 8; ++dt) {
    const long colb = (long)h * HD + dt * 16 + q;
    attnb[(long)(qrow0 + 4 * g + 0) * HID + colb] = f2bu(oacc[dt][0] * rl0);
    attnb[(long)(qrow0 + 4 * g + 1) * HID + colb] = f2bu(oacc[dt][1] * rl1);
    attnb[(long)(qrow0 + 4 * g + 2) * HID + colb] = f2bu(oacc[dt][2] * rl2);
    attnb[(long)(qrow0 + 4 * g + 3) * HID + colb] = f2bu(oacc[dt][3] * rl3);
  }
}

extern "C" void kernel_launch(void* const* d_in, const int* in_sizes, int n_in,
                              void* d_out, int out_size, void* d_ws, size_t ws_size,
                              hipStream_t stream)
{
  const float* x  = (const float*)d_in[0];
  const float* wq = (const float*)d_in[1];
  const float* bq = (const float*)d_in[2];
  const float* wk = (const float*)d_in[3];
  const float* bk = (const float*)d_in[4];
  const float* wv = (const float*)d_in[5];
  const float* bv = (const float*)d_in[6];
  const float* wo = (const float*)d_in[7];
  const float* bo = (const float*)d_in[8];

  const long NEL = (long)HID * HID;
  unsigned short* Xb   = (unsigned short*)d_ws;
  unsigned short* Wqkv = Xb + NEL;
  unsigned short* Wob  = Wqkv + 3 * NEL;
  unsigned short* Qbuf = Wob + NEL;
  unsigned short* Kbuf = Qbuf + NEL;
  unsigned short* VTb  = Kbuf + NEL;
  unsigned short* Attn = VTb + NEL;

  cvt_kernel<<<dim3(512, 5), 256, 0, stream>>>(
      x, wq, wk, wv, wo, Xb, Wqkv, Wqkv + NEL, Wqkv + 2 * NEL, Wob, (int)NEL);

  gemm97<4><<<dim3(48, 16), 256, 32768, stream>>>(
      Xb, Wqkv, bq, bk, bv, Qbuf, Kbuf, VTb, nullptr, SEQ, 3 * HID, HID);

  flash_attn<<<dim3(512), 256, 0, stream>>>(Qbuf, Kbuf, VTb, Attn);

  gemm128<3><<<dim3(16, 32), 256, 49152, stream>>>(
      Attn, Wob, bo, nullptr, nullptr, nullptr, nullptr, nullptr,
      (float*)d_out, SEQ, HID, HID);
}